// Round 1
// baseline (409.382 us; speedup 1.0000x reference)
//
#include <hip/hip_runtime.h>
#include <math.h>

typedef __attribute__((ext_vector_type(8))) __bf16 bf16x8;
typedef __attribute__((ext_vector_type(4))) __bf16 bf16x4;
typedef __attribute__((ext_vector_type(4))) float f32x4;

#define TSEQ 2048
#define HDIM 3584
#define NQH  16
#define NKVH 8
#define DH   256
#define WIN  1024
#define QKD  (NQH * DH)   /* 4096 */
#define KVD  (NKVH * DH)  /* 2048 */

__device__ __forceinline__ void gload_lds16(const void* g, void* l) {
  __builtin_amdgcn_global_load_lds(
      (const __attribute__((address_space(1))) void*)g,
      (__attribute__((address_space(3))) void*)l, 16, 0, 0);
}

// ---------------- prep kernels ----------------

__global__ void cvt_bf16_kernel(const float* __restrict__ in,
                                __bf16* __restrict__ out, long n) {
  long i = ((long)blockIdx.x * blockDim.x + threadIdx.x) * 4;
  if (i >= n) return;
  float4 v = *reinterpret_cast<const float4*>(in + i);
  bf16x4 o4;
  o4.x = (__bf16)v.x; o4.y = (__bf16)v.y; o4.z = (__bf16)v.z; o4.w = (__bf16)v.w;
  *reinterpret_cast<bf16x4*>(out + i) = o4;
}

// in: R x C fp32 (row-major)  ->  out: C x R bf16 (row-major)
__global__ void transpose_cvt_kernel(const float* __restrict__ in,
                                     __bf16* __restrict__ out, int R, int C) {
  __shared__ float tile[32][33];
  const int tx = threadIdx.x, ty = threadIdx.y;
  const int c0 = blockIdx.x * 32, r0 = blockIdx.y * 32;
#pragma unroll
  for (int i = 0; i < 4; ++i)
    tile[ty + i * 8][tx] = in[(size_t)(r0 + ty + i * 8) * C + (c0 + tx)];
  __syncthreads();
#pragma unroll
  for (int i = 0; i < 4; ++i)
    out[(size_t)(c0 + ty + i * 8) * R + (r0 + tx)] = (__bf16)tile[tx][ty + i * 8];
}

// in: R x C bf16 -> out: C x R bf16
__global__ void transpose_bf16_kernel(const __bf16* __restrict__ in,
                                      __bf16* __restrict__ out, int R, int C) {
  __shared__ __bf16 tile[32][33];
  const int tx = threadIdx.x, ty = threadIdx.y;
  const int c0 = blockIdx.x * 32, r0 = blockIdx.y * 32;
#pragma unroll
  for (int i = 0; i < 4; ++i)
    tile[ty + i * 8][tx] = in[(size_t)(r0 + ty + i * 8) * C + (c0 + tx)];
  __syncthreads();
#pragma unroll
  for (int i = 0; i < 4; ++i)
    out[(size_t)(c0 + ty + i * 8) * R + (r0 + tx)] = tile[tx][ty + i * 8];
}

__global__ void rope_table_kernel(const int* __restrict__ positions,
                                  float* __restrict__ ct,
                                  float* __restrict__ st) {
  int i = blockIdx.x * blockDim.x + threadIdx.x;
  if (i >= TSEQ * 128) return;
  int t = i >> 7, j = i & 127;
  // inv_freq = 10000^(-2j/256), computed in fp64, angle in fp32 like ref
  float invf = (float)exp((double)(-2 * j) * (9.210340371976184 / 256.0));
  float ang = (float)positions[t] * invf;
  ct[i] = cosf(ang);
  st[i] = sinf(ang);
}

// in-place RoPE on bf16 (T, heads, 256); also applies `scale`
__global__ void rope_apply_kernel(__bf16* __restrict__ x,
                                  const float* __restrict__ ct,
                                  const float* __restrict__ st,
                                  int heads, float scale, int total) {
  int i = blockIdx.x * blockDim.x + threadIdx.x;
  if (i >= total) return;
  int j = i & 127;
  int th = i >> 7;
  int t = th / heads;
  int head = th - t * heads;
  size_t base = ((size_t)t * heads + head) * DH + j;
  float x1 = (float)x[base], x2 = (float)x[base + 128];
  float c = ct[(t << 7) + j], s = st[(t << 7) + j];
  x[base]       = (__bf16)((x1 * c - x2 * s) * scale);
  x[base + 128] = (__bf16)((x2 * c + x1 * s) * scale);
}

// ---------------- GEMM (m97 structure: 128x128 tile, BK=32) ----------------
// A: M x K bf16 row-major (stride K). B: N x K bf16 row-major (stride K) == W^T.
// C[m][n] = sum_k A[m][k] * B[n][k].

template <typename CT>
__device__ __forceinline__ void gemm_body(const __bf16* __restrict__ A,
                                          const __bf16* __restrict__ B,
                                          CT* __restrict__ C,
                                          int K, int ldc, int row0, int col0) {
  __shared__ __bf16 Als[4096];
  __shared__ __bf16 Bls[4096];
  const int tid = threadIdx.x;
  const int wave = tid >> 6;
  const int lane = tid & 63;
  const int l16 = lane & 15;
  const int lg = lane >> 4;
  const int wr = wave >> 1;
  const int wc = wave & 1;

  const __bf16* Ag = A + (size_t)(row0 + wave * 16 + (lane >> 2)) * K + (lane & 3) * 8;
  const __bf16* Bg = B + (size_t)(col0 + wave * 16 + (lane >> 2)) * K + (lane & 3) * 8;
  __bf16* AlsW = Als + wave * 512;
  __bf16* BlsW = Bls + wave * 512;

  f32x4 acc[4][4] = {};

  for (int kt = 0; kt < K; kt += 32) {
    __syncthreads();
    gload_lds16(Ag + kt, AlsW);
    gload_lds16(Ag + (size_t)64 * K + kt, AlsW + 2048);
    gload_lds16(Bg + kt, BlsW);
    gload_lds16(Bg + (size_t)64 * K + kt, BlsW + 2048);
    __syncthreads();

    bf16x8 af[4], bfv[4];
#pragma unroll
    for (int mi = 0; mi < 4; ++mi)
      af[mi] = *reinterpret_cast<const bf16x8*>(&Als[(wr * 64 + mi * 16 + l16) * 32 + lg * 8]);
#pragma unroll
    for (int ni = 0; ni < 4; ++ni)
      bfv[ni] = *reinterpret_cast<const bf16x8*>(&Bls[(wc * 64 + ni * 16 + l16) * 32 + lg * 8]);
#pragma unroll
    for (int mi = 0; mi < 4; ++mi)
#pragma unroll
      for (int ni = 0; ni < 4; ++ni)
        acc[mi][ni] = __builtin_amdgcn_mfma_f32_16x16x32_bf16(af[mi], bfv[ni], acc[mi][ni], 0, 0, 0);
  }

#pragma unroll
  for (int mi = 0; mi < 4; ++mi)
#pragma unroll
    for (int ni = 0; ni < 4; ++ni)
#pragma unroll
      for (int r = 0; r < 4; ++r) {
        int row = row0 + wr * 64 + mi * 16 + lg * 4 + r;
        int col = col0 + wc * 64 + ni * 16 + l16;
        C[(size_t)row * ldc + col] = (CT)acc[mi][ni][r];
      }
}

// fused QKV: grid.x 0..63 -> [0,32)=Q, [32,48)=K, [48,64)=V; grid.y = M/128
__global__ __launch_bounds__(256, 3) void gemm_qkv_kernel(
    const __bf16* __restrict__ A,
    const __bf16* __restrict__ BqT, const __bf16* __restrict__ BkT,
    const __bf16* __restrict__ BvT,
    __bf16* __restrict__ Cq, __bf16* __restrict__ Ck, __bf16* __restrict__ Cv) {
  const int bx = blockIdx.x;
  const __bf16* B;
  __bf16* C;
  int ldc, col0;
  if (bx < 32)      { B = BqT; C = Cq; ldc = QKD; col0 = bx * 128; }
  else if (bx < 48) { B = BkT; C = Ck; ldc = KVD; col0 = (bx - 32) * 128; }
  else              { B = BvT; C = Cv; ldc = KVD; col0 = (bx - 48) * 128; }
  gemm_body<__bf16>(A, B, C, HDIM, ldc, blockIdx.y * 128, col0);
}

__global__ __launch_bounds__(256, 3) void gemm_out_kernel(
    const __bf16* __restrict__ A, const __bf16* __restrict__ B,
    float* __restrict__ C) {
  gemm_body<float>(A, B, C, QKD, HDIM, blockIdx.y * 128, blockIdx.x * 128);
}

// ---------------- flash attention ----------------
// grid = (32 q-tiles of 64, 16 q-heads), 256 threads (4 waves x 16 q-rows).
// q: (T, 4096) bf16 (rope'd, pre-scaled). k: (T, 2048) bf16 (rope'd).
// vt: (2048, T) bf16 = V^T per head (row = h*256+d). o: (T, 4096) bf16.
__global__ __launch_bounds__(256, 2) void attn_kernel(
    const __bf16* __restrict__ q, const __bf16* __restrict__ k,
    const __bf16* __restrict__ vt, __bf16* __restrict__ o) {
  __shared__ __bf16 Klds[64][264];   // keys x d, +8 pad
  __shared__ __bf16 Vlds[256][72];   // d x keys, +8 pad
  __shared__ __bf16 Plds[4][16][72]; // per-wave P round-trip

  const int tid = threadIdx.x;
  const int wave = tid >> 6;
  const int lane = tid & 63;
  const int l16 = lane & 15;
  const int lg = lane >> 4;
  const int qh = blockIdx.y;
  const int h = qh >> 1;
  const int q0 = blockIdx.x << 6;
  const int qr = q0 + wave * 16;

  bf16x8 qf[8];
  {
    const __bf16* qp = q + (size_t)(qr + l16) * QKD + qh * DH + lg * 8;
#pragma unroll
    for (int ds = 0; ds < 8; ++ds)
      qf[ds] = *reinterpret_cast<const bf16x8*>(qp + ds * 32);
  }

  f32x4 accO[16] = {};
  float m_run[4] = {-1e30f, -1e30f, -1e30f, -1e30f};
  float l_run[4] = {0.f, 0.f, 0.f, 0.f};

  int t_lo = q0 - (WIN - 1);
  if (t_lo < 0) t_lo = 0;
  t_lo &= ~63;

  for (int t0 = t_lo; t0 <= q0; t0 += 64) {
    __syncthreads();
    {
      const __bf16* kg = k + (size_t)t0 * KVD + h * DH;
#pragma unroll
      for (int it = 0; it < 8; ++it) {
        int c = tid + it * 256;
        int row = c >> 5, col = (c & 31) * 8;
        *reinterpret_cast<bf16x8*>(&Klds[row][col]) =
            *reinterpret_cast<const bf16x8*>(kg + (size_t)row * KVD + col);
      }
      const __bf16* vg = vt + (size_t)(h * DH) * TSEQ + t0;
#pragma unroll
      for (int it = 0; it < 8; ++it) {
        int c = tid + it * 256;
        int row = c >> 3, col = (c & 7) * 8;
        *reinterpret_cast<bf16x8*>(&Vlds[row][col]) =
            *reinterpret_cast<const bf16x8*>(vg + (size_t)row * TSEQ + col);
      }
    }
    __syncthreads();

    // S = Q K^T for this wave's 16 rows x 64 keys
    f32x4 accS[4] = {};
#pragma unroll
    for (int nt = 0; nt < 4; ++nt)
#pragma unroll
      for (int ds = 0; ds < 8; ++ds) {
        bf16x8 kf = *reinterpret_cast<const bf16x8*>(&Klds[nt * 16 + l16][ds * 32 + lg * 8]);
        accS[nt] = __builtin_amdgcn_mfma_f32_16x16x32_bf16(qf[ds], kf, accS[nt], 0, 0, 0);
      }

    // softcap + window mask + online softmax
    float pv[4][4];
    float mt[4] = {-1e30f, -1e30f, -1e30f, -1e30f};
#pragma unroll
    for (int nt = 0; nt < 4; ++nt) {
      int key = t0 + nt * 16 + l16;
#pragma unroll
      for (int r = 0; r < 4; ++r) {
        int row = qr + lg * 4 + r;
        float s = 50.f * tanhf(accS[nt][r] * 0.02f);
        bool valid = (key <= row) && (row - key < WIN);
        s = valid ? s : -1e30f;
        pv[nt][r] = s;
        mt[r] = fmaxf(mt[r], s);
      }
    }
#pragma unroll
    for (int off = 1; off < 16; off <<= 1)
#pragma unroll
      for (int r = 0; r < 4; ++r)
        mt[r] = fmaxf(mt[r], __shfl_xor(mt[r], off));

    float rs[4];
#pragma unroll
    for (int r = 0; r < 4; ++r) {
      float mn = fmaxf(m_run[r], mt[r]);
      float sc = __expf(m_run[r] - mn);
      m_run[r] = mn;
      l_run[r] *= sc;
      float s0 = 0.f;
#pragma unroll
      for (int nt = 0; nt < 4; ++nt) {
        float p = (pv[nt][r] > -1e29f) ? __expf(pv[nt][r] - mn) : 0.f;
        pv[nt][r] = p;
        s0 += p;
      }
      rs[r] = s0;
#pragma unroll
      for (int nt2 = 0; nt2 < 16; ++nt2)
        accO[nt2][r] *= sc;
    }
#pragma unroll
    for (int off = 1; off < 16; off <<= 1)
#pragma unroll
      for (int r = 0; r < 4; ++r)
        rs[r] += __shfl_xor(rs[r], off);
#pragma unroll
    for (int r = 0; r < 4; ++r)
      l_run[r] += rs[r];

    // P -> LDS (to reach MFMA A-layout), then PV
#pragma unroll
    for (int nt = 0; nt < 4; ++nt)
#pragma unroll
      for (int r = 0; r < 4; ++r)
        Plds[wave][lg * 4 + r][nt * 16 + l16] = (__bf16)pv[nt][r];

#pragma unroll
    for (int ks = 0; ks < 2; ++ks) {
      bf16x8 pa = *reinterpret_cast<const bf16x8*>(&Plds[wave][l16][ks * 32 + lg * 8]);
#pragma unroll
      for (int nt2 = 0; nt2 < 16; ++nt2) {
        bf16x8 vb = *reinterpret_cast<const bf16x8*>(&Vlds[nt2 * 16 + l16][ks * 32 + lg * 8]);
        accO[nt2] = __builtin_amdgcn_mfma_f32_16x16x32_bf16(pa, vb, accO[nt2], 0, 0, 0);
      }
    }
  }

#pragma unroll
  for (int r = 0; r < 4; ++r) {
    float inv_l = 1.f / l_run[r];
    int row = qr + lg * 4 + r;
#pragma unroll
    for (int nt2 = 0; nt2 < 16; ++nt2)
      o[(size_t)row * QKD + qh * DH + nt2 * 16 + l16] = (__bf16)(accO[nt2][r] * inv_l);
  }
}

// ---------------- launcher ----------------

extern "C" void kernel_launch(void* const* d_in, const int* in_sizes, int n_in,
                              void* d_out, int out_size, void* d_ws, size_t ws_size,
                              hipStream_t stream) {
  const float* hs = (const float*)d_in[0];
  const float* Wq = (const float*)d_in[1];
  const float* Wk = (const float*)d_in[2];
  const float* Wv = (const float*)d_in[3];
  const float* Wo = (const float*)d_in[4];
  const int* positions = (const int*)d_in[5];
  float* out = (float*)d_out;

  char* ws = (char*)d_ws;
  const size_t SZ_HS  = (size_t)TSEQ * HDIM * 2;
  const size_t SZ_WQT = (size_t)QKD * HDIM * 2;
  const size_t SZ_WKT = (size_t)KVD * HDIM * 2;
  const size_t SZ_WOT = (size_t)HDIM * QKD * 2;
  const size_t SZ_Q   = (size_t)TSEQ * QKD * 2;
  const size_t SZ_KV  = (size_t)TSEQ * KVD * 2;
  const size_t SZ_TBL = (size_t)TSEQ * 128 * 4;

  __bf16* hs_bf = (__bf16*)ws; ws += SZ_HS;
  __bf16* WqT   = (__bf16*)ws; ws += SZ_WQT;
  __bf16* WkT   = (__bf16*)ws; ws += SZ_WKT;
  __bf16* WvT   = (__bf16*)ws; ws += SZ_WKT;
  __bf16* WoT   = (__bf16*)ws; ws += SZ_WOT;
  __bf16* q_bf  = (__bf16*)ws; ws += SZ_Q;
  __bf16* k_bf  = (__bf16*)ws; ws += SZ_KV;
  __bf16* v_bf  = (__bf16*)ws; ws += SZ_KV;
  __bf16* vt_bf = (__bf16*)ws; ws += SZ_KV;
  __bf16* o_bf  = (__bf16*)ws; ws += SZ_Q;
  float*  cost  = (float*)ws;  ws += SZ_TBL;
  float*  sint  = (float*)ws;  ws += SZ_TBL;
  if ((size_t)(ws - (char*)d_ws) > ws_size) return;  // ws too small: fail visibly

  // prep
  cvt_bf16_kernel<<<(TSEQ * HDIM) / 1024, 256, 0, stream>>>(hs, hs_bf, (long)TSEQ * HDIM);
  transpose_cvt_kernel<<<dim3(QKD / 32, HDIM / 32), dim3(32, 8), 0, stream>>>(Wq, WqT, HDIM, QKD);
  transpose_cvt_kernel<<<dim3(KVD / 32, HDIM / 32), dim3(32, 8), 0, stream>>>(Wk, WkT, HDIM, KVD);
  transpose_cvt_kernel<<<dim3(KVD / 32, HDIM / 32), dim3(32, 8), 0, stream>>>(Wv, WvT, HDIM, KVD);
  transpose_cvt_kernel<<<dim3(HDIM / 32, QKD / 32), dim3(32, 8), 0, stream>>>(Wo, WoT, QKD, HDIM);
  rope_table_kernel<<<(TSEQ * 128) / 256, 256, 0, stream>>>(positions, cost, sint);

  // QKV projection (fused)
  gemm_qkv_kernel<<<dim3(64, TSEQ / 128), 256, 0, stream>>>(hs_bf, WqT, WkT, WvT,
                                                            q_bf, k_bf, v_bf);
  // RoPE (+ q scale 1/16), V transpose
  rope_apply_kernel<<<(TSEQ * NQH * 128) / 256, 256, 0, stream>>>(q_bf, cost, sint, NQH, 0.0625f, TSEQ * NQH * 128);
  rope_apply_kernel<<<(TSEQ * NKVH * 128) / 256, 256, 0, stream>>>(k_bf, cost, sint, NKVH, 1.0f, TSEQ * NKVH * 128);
  transpose_bf16_kernel<<<dim3(KVD / 32, TSEQ / 32), dim3(32, 8), 0, stream>>>(v_bf, vt_bf, TSEQ, KVD);

  // attention
  attn_kernel<<<dim3(TSEQ / 64, NQH), 256, 0, stream>>>(q_bf, k_bf, vt_bf, o_bf);

  // output projection (fp32 out)
  gemm_out_kernel<<<dim3(HDIM / 128, TSEQ / 128), 256, 0, stream>>>(o_bf, WoT, out);
}

// Round 2
// 388.063 us; speedup vs baseline: 1.0549x; 1.0549x over previous
//
#include <hip/hip_runtime.h>
#include <math.h>

typedef __attribute__((ext_vector_type(8))) __bf16 bf16x8;
typedef __attribute__((ext_vector_type(4))) __bf16 bf16x4;
typedef __attribute__((ext_vector_type(4))) float f32x4;

#define TSEQ 2048
#define HDIM 3584
#define NQH  16
#define NKVH 8
#define DH   256
#define WIN  1024
#define QKD  (NQH * DH)   /* 4096 */
#define KVD  (NKVH * DH)  /* 2048 */
#define QKVN 8192         /* fused QKV output width */

#define MFMA __builtin_amdgcn_mfma_f32_16x16x32_bf16

__device__ __forceinline__ void gload_lds16(const void* g, void* l) {
  __builtin_amdgcn_global_load_lds(
      (const __attribute__((address_space(1))) void*)g,
      (__attribute__((address_space(3))) void*)l, 16, 0, 0);
}

// ---------------- prep kernels ----------------

__global__ void cvt_bf16_kernel(const float* __restrict__ in,
                                __bf16* __restrict__ out, long n) {
  long i = ((long)blockIdx.x * blockDim.x + threadIdx.x) * 4;
  if (i >= n) return;
  float4 v = *reinterpret_cast<const float4*>(in + i);
  bf16x4 o4;
  o4.x = (__bf16)v.x; o4.y = (__bf16)v.y; o4.z = (__bf16)v.z; o4.w = (__bf16)v.w;
  *reinterpret_cast<bf16x4*>(out + i) = o4;
}

// in: R x C fp32 (row-major)  ->  out: C x R bf16 (row-major)
__global__ void transpose_cvt_kernel(const float* __restrict__ in,
                                     __bf16* __restrict__ out, int R, int C) {
  __shared__ float tile[32][33];
  const int tx = threadIdx.x, ty = threadIdx.y;
  const int c0 = blockIdx.x * 32, r0 = blockIdx.y * 32;
#pragma unroll
  for (int i = 0; i < 4; ++i)
    tile[ty + i * 8][tx] = in[(size_t)(r0 + ty + i * 8) * C + (c0 + tx)];
  __syncthreads();
#pragma unroll
  for (int i = 0; i < 4; ++i)
    out[(size_t)(c0 + ty + i * 8) * R + (r0 + tx)] = (__bf16)tile[tx][ty + i * 8];
}

// in: R x C bf16 (leading dim ldin) -> out: C x R bf16 (leading dim ldout)
__global__ void transpose_bf16_kernel(const __bf16* __restrict__ in,
                                      __bf16* __restrict__ out, int ldin, int ldout) {
  __shared__ __bf16 tile[32][33];
  const int tx = threadIdx.x, ty = threadIdx.y;
  const int c0 = blockIdx.x * 32, r0 = blockIdx.y * 32;
#pragma unroll
  for (int i = 0; i < 4; ++i)
    tile[ty + i * 8][tx] = in[(size_t)(r0 + ty + i * 8) * ldin + (c0 + tx)];
  __syncthreads();
#pragma unroll
  for (int i = 0; i < 4; ++i)
    out[(size_t)(c0 + ty + i * 8) * ldout + (r0 + tx)] = tile[tx][ty + i * 8];
}

__global__ void rope_table_kernel(const int* __restrict__ positions,
                                  float* __restrict__ ct,
                                  float* __restrict__ st) {
  int i = blockIdx.x * blockDim.x + threadIdx.x;
  if (i >= TSEQ * 128) return;
  int t = i >> 7, j = i & 127;
  float invf = (float)exp((double)(-2 * j) * (9.210340371976184 / 256.0));
  float ang = (float)positions[t] * invf;
  ct[i] = cosf(ang);
  st[i] = sinf(ang);
}

// in-place RoPE on bf16 rows of leading-dim ld; also applies `scale`
__global__ void rope_apply_kernel(__bf16* __restrict__ x,
                                  const float* __restrict__ ct,
                                  const float* __restrict__ st,
                                  int heads, int ld, float scale, int total) {
  int i = blockIdx.x * blockDim.x + threadIdx.x;
  if (i >= total) return;
  int j = i & 127;
  int th = i >> 7;
  int t = th / heads;
  int head = th - t * heads;
  size_t base = (size_t)t * ld + head * DH + j;
  float x1 = (float)x[base], x2 = (float)x[base + 128];
  float c = ct[(t << 7) + j], s = st[(t << 7) + j];
  x[base]       = (__bf16)((x1 * c - x2 * s) * scale);
  x[base + 128] = (__bf16)((x2 * c + x1 * s) * scale);
}

// ---------------- 256x256 8-phase GEMM ----------------
// A: M x K bf16 (ld K). B: N x K bf16 (ld K). C[m][n] = sum_k A[m][k]*B[n][k].
// 512 threads = 8 waves (2Mx4N). BK=64. LDS swizzle: kbyte ^= (row&7)<<4,
// applied on the pre-swizzled global source (linear LDS dest) and on ds_read.

__device__ __forceinline__ void stage_half(const __bf16* __restrict__ gbase,
                                           int row0, int ldg, int k0,
                                           __bf16* lds_half, int tid) {
  const int lane = tid & 63;
  const int w = tid >> 6;
  const int lr = lane >> 3;                    // row&7 within half
  const int swzcol = ((lane & 7) ^ lr) << 3;   // pre-swizzled source column
  const __bf16* g = gbase + (size_t)(row0 + w * 8 + lr) * ldg + k0 + swzcol;
  __bf16* l = lds_half + w * 512;              // wave-uniform dest (elements)
  gload_lds16(g, l);
  gload_lds16(g + (size_t)64 * ldg, l + 4096);
}

template <typename CT>
__global__ __launch_bounds__(512, 2) void gemm256_kernel(
    const __bf16* __restrict__ A, const __bf16* __restrict__ B,
    CT* __restrict__ C, int K, int ldc, int nbx) {
  __shared__ __bf16 lds[2][2][2][8192];  // [buf][A=0/B=1][half][128*64]

  const int nwg = gridDim.x;
  const int per = nwg >> 3;
  const int wg = (blockIdx.x & 7) * per + (blockIdx.x >> 3);  // XCD swizzle
  const int row0 = (wg / nbx) * 256;
  const int col0 = (wg % nbx) * 256;

  const int tid = threadIdx.x;
  const int lane = tid & 63, w = tid >> 6;
  const int wr = w >> 2, wc = w & 3;
  const int l15 = lane & 15, lg = lane >> 4;
  const int swz = (lane & 7) << 3;
  const int kxa = (lg * 8) ^ swz;        // ksub 0
  const int kxb = (32 + lg * 8) ^ swz;   // ksub 1
  const int bro = (wc & 1) * 64;

  const __bf16* Ablk = A + (size_t)row0 * K;
  const __bf16* Bblk = B + (size_t)col0 * K;

  f32x4 acc[8][4] = {};
  const int NT = K >> 6;

  // prologue: tile0 all 4 halves -> buf0; tile1 A-halves -> buf1
  stage_half(Ablk, 0,   K, 0,  &lds[0][0][0][0], tid);
  stage_half(Ablk, 128, K, 0,  &lds[0][0][1][0], tid);
  stage_half(Bblk, 0,   K, 0,  &lds[0][1][0][0], tid);
  stage_half(Bblk, 128, K, 0,  &lds[0][1][1][0], tid);
  stage_half(Ablk, 0,   K, 64, &lds[1][0][0][0], tid);
  stage_half(Ablk, 128, K, 64, &lds[1][0][1][0], tid);
  asm volatile("s_waitcnt vmcnt(4)" ::: "memory");
  __builtin_amdgcn_s_barrier();

  bf16x8 a0[4][2], a1[4][2], b0[2][2], b1[2][2];

  for (int t = 0; t < NT; ++t) {
    const int cur = t & 1, nxt = cur ^ 1;
    const __bf16* Ah = &lds[cur][0][wr][0];
    const __bf16* Bh = &lds[cur][1][wc >> 1][0];

    // ---- phase 0: read A0 (m0-3), B0 (n0-1); stage (t+1) B-h0 -> nxt
#pragma unroll
    for (int m = 0; m < 4; ++m) {
      const __bf16* p = Ah + (m * 16 + l15) * 64;
      a0[m][0] = *(const bf16x8*)(p + kxa);
      a0[m][1] = *(const bf16x8*)(p + kxb);
    }
#pragma unroll
    for (int n = 0; n < 2; ++n) {
      const __bf16* p = Bh + (bro + n * 16 + l15) * 64;
      b0[n][0] = *(const bf16x8*)(p + kxa);
      b0[n][1] = *(const bf16x8*)(p + kxb);
    }
    if (t + 1 < NT) stage_half(Bblk, 0, K, (t + 1) * 64, &lds[nxt][1][0][0], tid);
    __builtin_amdgcn_s_barrier();
    __builtin_amdgcn_s_setprio(1);
#pragma unroll
    for (int m = 0; m < 4; ++m)
#pragma unroll
      for (int n = 0; n < 2; ++n) {
        acc[m][n] = MFMA(a0[m][0], b0[n][0], acc[m][n], 0, 0, 0);
        acc[m][n] = MFMA(a0[m][1], b0[n][1], acc[m][n], 0, 0, 0);
      }
    __builtin_amdgcn_s_setprio(0);
    __builtin_amdgcn_s_barrier();

    // ---- phase 1: read A1 (m4-7); stage (t+1) B-h1 -> nxt
#pragma unroll
    for (int m = 0; m < 4; ++m) {
      const __bf16* p = Ah + ((m + 4) * 16 + l15) * 64;
      a1[m][0] = *(const bf16x8*)(p + kxa);
      a1[m][1] = *(const bf16x8*)(p + kxb);
    }
    if (t + 1 < NT) stage_half(Bblk, 128, K, (t + 1) * 64, &lds[nxt][1][1][0], tid);
    __builtin_amdgcn_s_barrier();
    __builtin_amdgcn_s_setprio(1);
#pragma unroll
    for (int m = 0; m < 4; ++m)
#pragma unroll
      for (int n = 0; n < 2; ++n) {
        acc[m + 4][n] = MFMA(a1[m][0], b0[n][0], acc[m + 4][n], 0, 0, 0);
        acc[m + 4][n] = MFMA(a1[m][1], b0[n][1], acc[m + 4][n], 0, 0, 0);
      }
    __builtin_amdgcn_s_setprio(0);
    __builtin_amdgcn_s_barrier();

    // ---- phase 2: read B1 (n2-3); stage (t+2) A-h0 -> cur
#pragma unroll
    for (int n = 0; n < 2; ++n) {
      const __bf16* p = Bh + (bro + (n + 2) * 16 + l15) * 64;
      b1[n][0] = *(const bf16x8*)(p + kxa);
      b1[n][1] = *(const bf16x8*)(p + kxb);
    }
    if (t + 2 < NT) stage_half(Ablk, 0, K, (t + 2) * 64, &lds[cur][0][0][0], tid);
    __builtin_amdgcn_s_barrier();
    __builtin_amdgcn_s_setprio(1);
#pragma unroll
    for (int m = 0; m < 4; ++m)
#pragma unroll
      for (int n = 0; n < 2; ++n) {
        acc[m + 4][n + 2] = MFMA(a1[m][0], b1[n][0], acc[m + 4][n + 2], 0, 0, 0);
        acc[m + 4][n + 2] = MFMA(a1[m][1], b1[n][1], acc[m + 4][n + 2], 0, 0, 0);
      }
    __builtin_amdgcn_s_setprio(0);
    __builtin_amdgcn_s_barrier();

    // ---- phase 3: stage (t+2) A-h1 -> cur; counted vmcnt (never 0 mid-loop)
    if (t + 2 < NT) {
      stage_half(Ablk, 128, K, (t + 2) * 64, &lds[cur][0][1][0], tid);
      asm volatile("s_waitcnt vmcnt(4)" ::: "memory");
    } else {
      asm volatile("s_waitcnt vmcnt(0)" ::: "memory");
    }
    __builtin_amdgcn_s_barrier();
    __builtin_amdgcn_s_setprio(1);
#pragma unroll
    for (int m = 0; m < 4; ++m)
#pragma unroll
      for (int n = 0; n < 2; ++n) {
        acc[m][n + 2] = MFMA(a0[m][0], b1[n][0], acc[m][n + 2], 0, 0, 0);
        acc[m][n + 2] = MFMA(a0[m][1], b1[n][1], acc[m][n + 2], 0, 0, 0);
      }
    __builtin_amdgcn_s_setprio(0);
    __builtin_amdgcn_s_barrier();
  }

#pragma unroll
  for (int m = 0; m < 8; ++m)
#pragma unroll
    for (int n = 0; n < 4; ++n)
#pragma unroll
      for (int r = 0; r < 4; ++r) {
        int row = row0 + wr * 128 + m * 16 + lg * 4 + r;
        int col = col0 + wc * 64 + n * 16 + l15;
        C[(size_t)row * ldc + col] = (CT)acc[m][n][r];
      }
}

// ---------------- flash attention ----------------
// grid = (32 q-tiles of 64, 16 q-heads), 256 threads (4 waves x 16 q-rows).
// q/k live in the fused qkv buffer (ld 8192). vt: (2048, T) = V^T per head.
__global__ __launch_bounds__(256, 2) void attn_kernel(
    const __bf16* __restrict__ q, const __bf16* __restrict__ k,
    const __bf16* __restrict__ vt, __bf16* __restrict__ o) {
  __shared__ __bf16 Klds[64][264];   // keys x d, +8 pad
  __shared__ __bf16 Vlds[256][72];   // d x keys, +8 pad
  __shared__ __bf16 Plds[4][16][72]; // per-wave P round-trip

  const int tid = threadIdx.x;
  const int wave = tid >> 6;
  const int lane = tid & 63;
  const int l16 = lane & 15;
  const int lg = lane >> 4;
  const int qh = blockIdx.y;
  const int h = qh >> 1;
  const int q0 = blockIdx.x << 6;
  const int qr = q0 + wave * 16;

  bf16x8 qf[8];
  {
    const __bf16* qp = q + (size_t)(qr + l16) * QKVN + qh * DH + lg * 8;
#pragma unroll
    for (int ds = 0; ds < 8; ++ds)
      qf[ds] = *reinterpret_cast<const bf16x8*>(qp + ds * 32);
  }

  f32x4 accO[16] = {};
  float m_run[4] = {-1e30f, -1e30f, -1e30f, -1e30f};
  float l_run[4] = {0.f, 0.f, 0.f, 0.f};

  int t_lo = q0 - (WIN - 1);
  if (t_lo < 0) t_lo = 0;
  t_lo &= ~63;

  for (int t0 = t_lo; t0 <= q0; t0 += 64) {
    __syncthreads();
    {
      const __bf16* kg = k + (size_t)t0 * QKVN + h * DH;
#pragma unroll
      for (int it = 0; it < 8; ++it) {
        int c = tid + it * 256;
        int row = c >> 5, col = (c & 31) * 8;
        *reinterpret_cast<bf16x8*>(&Klds[row][col]) =
            *reinterpret_cast<const bf16x8*>(kg + (size_t)row * QKVN + col);
      }
      const __bf16* vg = vt + (size_t)(h * DH) * TSEQ + t0;
#pragma unroll
      for (int it = 0; it < 8; ++it) {
        int c = tid + it * 256;
        int row = c >> 3, col = (c & 7) * 8;
        *reinterpret_cast<bf16x8*>(&Vlds[row][col]) =
            *reinterpret_cast<const bf16x8*>(vg + (size_t)row * TSEQ + col);
      }
    }
    __syncthreads();

    f32x4 accS[4] = {};
#pragma unroll
    for (int nt = 0; nt < 4; ++nt)
#pragma unroll
      for (int ds = 0; ds < 8; ++ds) {
        bf16x8 kf = *reinterpret_cast<const bf16x8*>(&Klds[nt * 16 + l16][ds * 32 + lg * 8]);
        accS[nt] = MFMA(qf[ds], kf, accS[nt], 0, 0, 0);
      }

    float pv[4][4];
    float mt[4] = {-1e30f, -1e30f, -1e30f, -1e30f};
#pragma unroll
    for (int nt = 0; nt < 4; ++nt) {
      int key = t0 + nt * 16 + l16;
#pragma unroll
      for (int r = 0; r < 4; ++r) {
        int row = qr + lg * 4 + r;
        float s = 50.f * tanhf(accS[nt][r] * 0.02f);
        bool valid = (key <= row) && (row - key < WIN);
        s = valid ? s : -1e30f;
        pv[nt][r] = s;
        mt[r] = fmaxf(mt[r], s);
      }
    }
#pragma unroll
    for (int off = 1; off < 16; off <<= 1)
#pragma unroll
      for (int r = 0; r < 4; ++r)
        mt[r] = fmaxf(mt[r], __shfl_xor(mt[r], off));

    float rs[4];
#pragma unroll
    for (int r = 0; r < 4; ++r) {
      float mn = fmaxf(m_run[r], mt[r]);
      float sc = __expf(m_run[r] - mn);
      m_run[r] = mn;
      l_run[r] *= sc;
      float s0 = 0.f;
#pragma unroll
      for (int nt = 0; nt < 4; ++nt) {
        float p = (pv[nt][r] > -1e29f) ? __expf(pv[nt][r] - mn) : 0.f;
        pv[nt][r] = p;
        s0 += p;
      }
      rs[r] = s0;
#pragma unroll
      for (int nt2 = 0; nt2 < 16; ++nt2)
        accO[nt2][r] *= sc;
    }
#pragma unroll
    for (int off = 1; off < 16; off <<= 1)
#pragma unroll
      for (int r = 0; r < 4; ++r)
        rs[r] += __shfl_xor(rs[r], off);
#pragma unroll
    for (int r = 0; r < 4; ++r)
      l_run[r] += rs[r];

#pragma unroll
    for (int nt = 0; nt < 4; ++nt)
#pragma unroll
      for (int r = 0; r < 4; ++r)
        Plds[wave][lg * 4 + r][nt * 16 + l16] = (__bf16)pv[nt][r];

#pragma unroll
    for (int ks = 0; ks < 2; ++ks) {
      bf16x8 pa = *reinterpret_cast<const bf16x8*>(&Plds[wave][l16][ks * 32 + lg * 8]);
#pragma unroll
      for (int nt2 = 0; nt2 < 16; ++nt2) {
        bf16x8 vb = *reinterpret_cast<const bf16x8*>(&Vlds[nt2 * 16 + l16][ks * 32 + lg * 8]);
        accO[nt2] = MFMA(pa, vb, accO[nt2], 0, 0, 0);
      }
    }
  }

#pragma unroll
  for (int r = 0; r < 4; ++r) {
    float inv_l = 1.f / l_run[r];
    int row = qr + lg * 4 + r;
#pragma unroll
    for (int nt2 = 0; nt2 < 16; ++nt2)
      o[(size_t)row * QKD + qh * DH + nt2 * 16 + l16] = (__bf16)(accO[nt2][r] * inv_l);
  }
}

// ---------------- launcher ----------------

extern "C" void kernel_launch(void* const* d_in, const int* in_sizes, int n_in,
                              void* d_out, int out_size, void* d_ws, size_t ws_size,
                              hipStream_t stream) {
  const float* hs = (const float*)d_in[0];
  const float* Wq = (const float*)d_in[1];
  const float* Wk = (const float*)d_in[2];
  const float* Wv = (const float*)d_in[3];
  const float* Wo = (const float*)d_in[4];
  const int* positions = (const int*)d_in[5];
  float* out = (float*)d_out;

  char* ws = (char*)d_ws;
  const size_t SZ_HS  = (size_t)TSEQ * HDIM * 2;
  const size_t SZ_WQT = (size_t)QKD * HDIM * 2;
  const size_t SZ_WKT = (size_t)KVD * HDIM * 2;
  const size_t SZ_WOT = (size_t)HDIM * QKD * 2;
  const size_t SZ_QKV = (size_t)TSEQ * QKVN * 2;
  const size_t SZ_O   = (size_t)TSEQ * QKD * 2;
  const size_t SZ_TBL = (size_t)TSEQ * 128 * 4;

  __bf16* hs_bf = (__bf16*)ws; ws += SZ_HS;
  __bf16* WqT   = (__bf16*)ws; ws += SZ_WQT;   // WqT/WkT/WvT contiguous -> fused B (8192 x 3584)
  __bf16* WkT   = (__bf16*)ws; ws += SZ_WKT;
  __bf16* WvT   = (__bf16*)ws; ws += SZ_WKT;
  __bf16* WoT   = (__bf16*)ws; ws += SZ_WOT;
  __bf16* qkv   = (__bf16*)ws; ws += SZ_QKV;
  __bf16* o_bf  = (__bf16*)ws; ws += SZ_O;
  float*  cost  = (float*)ws;  ws += SZ_TBL;
  float*  sint  = (float*)ws;  ws += SZ_TBL;
  __bf16* vt_bf = hs_bf;  // overlay: hs_bf is dead after the QKV GEMM
  if ((size_t)(ws - (char*)d_ws) > ws_size) return;

  // prep
  cvt_bf16_kernel<<<(TSEQ * HDIM) / 1024, 256, 0, stream>>>(hs, hs_bf, (long)TSEQ * HDIM);
  transpose_cvt_kernel<<<dim3(QKD / 32, HDIM / 32), dim3(32, 8), 0, stream>>>(Wq, WqT, HDIM, QKD);
  transpose_cvt_kernel<<<dim3(KVD / 32, HDIM / 32), dim3(32, 8), 0, stream>>>(Wk, WkT, HDIM, KVD);
  transpose_cvt_kernel<<<dim3(KVD / 32, HDIM / 32), dim3(32, 8), 0, stream>>>(Wv, WvT, HDIM, KVD);
  transpose_cvt_kernel<<<dim3(HDIM / 32, QKD / 32), dim3(32, 8), 0, stream>>>(Wo, WoT, QKD, HDIM);
  rope_table_kernel<<<(TSEQ * 128) / 256, 256, 0, stream>>>(positions, cost, sint);

  // fused QKV projection: M=2048, N=8192, K=3584 -> 256 blocks (1/CU)
  gemm256_kernel<__bf16><<<256, 512, 0, stream>>>(hs_bf, WqT, qkv, HDIM, QKVN, 32);

  // RoPE (+ q scale 1/16), V transpose (into hs_bf overlay)
  rope_apply_kernel<<<(TSEQ * NQH * 128) / 256, 256, 0, stream>>>(qkv, cost, sint, NQH, QKVN, 0.0625f, TSEQ * NQH * 128);
  rope_apply_kernel<<<(TSEQ * NKVH * 128) / 256, 256, 0, stream>>>(qkv + QKD, cost, sint, NKVH, QKVN, 1.0f, TSEQ * NKVH * 128);
  transpose_bf16_kernel<<<dim3(KVD / 32, TSEQ / 32), dim3(32, 8), 0, stream>>>(qkv + QKD + KVD, vt_bf, QKVN, TSEQ);

  // attention
  attn_kernel<<<dim3(TSEQ / 64, NQH), 256, 0, stream>>>(qkv, qkv + QKD, vt_bf, o_bf);

  // output projection: M=2048, N=3584, K=4096 -> 112 blocks
  gemm256_kernel<float><<<112, 512, 0, stream>>>(o_bf, WoT, out, QKD, HDIM, 14);
}

// Round 3
// 356.571 us; speedup vs baseline: 1.1481x; 1.0883x over previous
//
#include <hip/hip_runtime.h>
#include <math.h>

typedef __attribute__((ext_vector_type(8))) __bf16 bf16x8;
typedef __attribute__((ext_vector_type(4))) __bf16 bf16x4;
typedef __attribute__((ext_vector_type(4))) float f32x4;

#define TSEQ 2048
#define HDIM 3584
#define NQH  16
#define NKVH 8
#define DH   256
#define WIN  1024
#define QKD  (NQH * DH)   /* 4096 */
#define KVD  (NKVH * DH)  /* 2048 */
#define QKVN 8192         /* fused QKV output width */

#define MFMA __builtin_amdgcn_mfma_f32_16x16x32_bf16

__device__ __forceinline__ void gload_lds16(const void* g, void* l) {
  __builtin_amdgcn_global_load_lds(
      (const __attribute__((address_space(1))) void*)g,
      (__attribute__((address_space(3))) void*)l, 16, 0, 0);
}

// ---------------- prep kernels ----------------

__global__ void cvt_bf16_kernel(const float* __restrict__ in,
                                __bf16* __restrict__ out, long n) {
  long i = ((long)blockIdx.x * blockDim.x + threadIdx.x) * 4;
  if (i >= n) return;
  float4 v = *reinterpret_cast<const float4*>(in + i);
  bf16x4 o4;
  o4.x = (__bf16)v.x; o4.y = (__bf16)v.y; o4.z = (__bf16)v.z; o4.w = (__bf16)v.w;
  *reinterpret_cast<bf16x4*>(out + i) = o4;
}

// in: R x C fp32 (row-major)  ->  out: C x R bf16 (row-major)
__global__ void transpose_cvt_kernel(const float* __restrict__ in,
                                     __bf16* __restrict__ out, int R, int C) {
  __shared__ float tile[32][33];
  const int tx = threadIdx.x, ty = threadIdx.y;
  const int c0 = blockIdx.x * 32, r0 = blockIdx.y * 32;
#pragma unroll
  for (int i = 0; i < 4; ++i)
    tile[ty + i * 8][tx] = in[(size_t)(r0 + ty + i * 8) * C + (c0 + tx)];
  __syncthreads();
#pragma unroll
  for (int i = 0; i < 4; ++i)
    out[(size_t)(c0 + ty + i * 8) * R + (r0 + tx)] = (__bf16)tile[tx][ty + i * 8];
}

// in: R x C bf16 (leading dim ldin) -> out: C x R bf16 (leading dim ldout)
__global__ void transpose_bf16_kernel(const __bf16* __restrict__ in,
                                      __bf16* __restrict__ out, int ldin, int ldout) {
  __shared__ __bf16 tile[32][33];
  const int tx = threadIdx.x, ty = threadIdx.y;
  const int c0 = blockIdx.x * 32, r0 = blockIdx.y * 32;
#pragma unroll
  for (int i = 0; i < 4; ++i)
    tile[ty + i * 8][tx] = in[(size_t)(r0 + ty + i * 8) * ldin + (c0 + tx)];
  __syncthreads();
#pragma unroll
  for (int i = 0; i < 4; ++i)
    out[(size_t)(c0 + ty + i * 8) * ldout + (r0 + tx)] = tile[tx][ty + i * 8];
}

__global__ void rope_table_kernel(const int* __restrict__ positions,
                                  float* __restrict__ ct,
                                  float* __restrict__ st) {
  int i = blockIdx.x * blockDim.x + threadIdx.x;
  if (i >= TSEQ * 128) return;
  int t = i >> 7, j = i & 127;
  float invf = (float)exp((double)(-2 * j) * (9.210340371976184 / 256.0));
  float ang = (float)positions[t] * invf;
  ct[i] = cosf(ang);
  st[i] = sinf(ang);
}

// in-place RoPE on bf16 rows of leading-dim ld; also applies `scale`
__global__ void rope_apply_kernel(__bf16* __restrict__ x,
                                  const float* __restrict__ ct,
                                  const float* __restrict__ st,
                                  int heads, int ld, float scale, int total) {
  int i = blockIdx.x * blockDim.x + threadIdx.x;
  if (i >= total) return;
  int j = i & 127;
  int th = i >> 7;
  int t = th / heads;
  int head = th - t * heads;
  size_t base = (size_t)t * ld + head * DH + j;
  float x1 = (float)x[base], x2 = (float)x[base + 128];
  float c = ct[(t << 7) + j], s = st[(t << 7) + j];
  x[base]       = (__bf16)((x1 * c - x2 * s) * scale);
  x[base + 128] = (__bf16)((x2 * c + x1 * s) * scale);
}

// split-K reduce: out[i] = p0[i] + p1[i]  (fp32, float4-vectorized)
__global__ void reduce2_kernel(const float* __restrict__ p0,
                               const float* __restrict__ p1,
                               float* __restrict__ out, int n4) {
  int stride = gridDim.x * blockDim.x;
  for (int i = blockIdx.x * blockDim.x + threadIdx.x; i < n4; i += stride) {
    float4 a = reinterpret_cast<const float4*>(p0)[i];
    float4 b = reinterpret_cast<const float4*>(p1)[i];
    a.x += b.x; a.y += b.y; a.z += b.z; a.w += b.w;
    reinterpret_cast<float4*>(out)[i] = a;
  }
}

// ---------------- 256x256 8-phase GEMM (split-K capable) ----------------
// A: M x K bf16 (ld lda). B: N x K bf16 (ld lda). C[m][n] = sum_k over slice.
// 512 threads = 8 waves (2Mx4N). BK=64. LDS swizzle: kbyte ^= (row&7)<<4,
// pre-swizzled global source (linear LDS dest) + swizzled ds_read.
// Grid = nslice * nrc blocks; nrc = 8 rows x (nrc/8) cols, col-major decode so
// each XCD owns a column-band (B panels L2-resident).

__device__ __forceinline__ void stage_half(const __bf16* __restrict__ gbase,
                                           int row0, int ldg, int k0,
                                           __bf16* lds_half, int tid) {
  const int lane = tid & 63;
  const int w = tid >> 6;
  const int lr = lane >> 3;                    // row&7 within half
  const int swzcol = ((lane & 7) ^ lr) << 3;   // pre-swizzled source column
  const __bf16* g = gbase + (size_t)(row0 + w * 8 + lr) * ldg + k0 + swzcol;
  __bf16* l = lds_half + w * 512;              // wave-uniform dest (elements)
  gload_lds16(g, l);
  gload_lds16(g + (size_t)64 * ldg, l + 4096);
}

template <typename CT>
__global__ __launch_bounds__(512, 2) void gemm256_kernel(
    const __bf16* __restrict__ A, const __bf16* __restrict__ B,
    CT* __restrict__ C, int lda, int Klen, int ldc, int nrc, size_t cstride) {
  __shared__ __bf16 lds[2][2][2][8192];  // [buf][A=0/B=1][half][128*64]

  const int nwg = gridDim.x;
  const int per = nwg >> 3;
  const int wg = (blockIdx.x & 7) * per + (blockIdx.x >> 3);  // XCD chunk swizzle
  const int kslice = wg / nrc;
  const int rem = wg - kslice * nrc;
  const int row0 = (rem & 7) * 256;        // col-major decode: XCD owns col-band
  const int col0 = (rem >> 3) * 256;
  const int k0 = kslice * Klen;
  CT* Cs = C + (size_t)kslice * cstride;

  const int tid = threadIdx.x;
  const int lane = tid & 63, w = tid >> 6;
  const int wr = w >> 2, wc = w & 3;
  const int l15 = lane & 15, lg = lane >> 4;
  const int swz = (lane & 7) << 3;
  const int kxa = (lg * 8) ^ swz;        // ksub 0
  const int kxb = (32 + lg * 8) ^ swz;   // ksub 1
  const int bro = (wc & 1) * 64;

  const __bf16* Ablk = A + (size_t)row0 * lda + k0;
  const __bf16* Bblk = B + (size_t)col0 * lda + k0;

  f32x4 acc[8][4] = {};
  const int NT = Klen >> 6;

  // prologue: tile0 all 4 halves -> buf0; tile1 A-halves -> buf1
  stage_half(Ablk, 0,   lda, 0,  &lds[0][0][0][0], tid);
  stage_half(Ablk, 128, lda, 0,  &lds[0][0][1][0], tid);
  stage_half(Bblk, 0,   lda, 0,  &lds[0][1][0][0], tid);
  stage_half(Bblk, 128, lda, 0,  &lds[0][1][1][0], tid);
  stage_half(Ablk, 0,   lda, 64, &lds[1][0][0][0], tid);
  stage_half(Ablk, 128, lda, 64, &lds[1][0][1][0], tid);
  asm volatile("s_waitcnt vmcnt(4)" ::: "memory");
  __builtin_amdgcn_s_barrier();

  bf16x8 a0[4][2], a1[4][2], b0[2][2], b1[2][2];

  for (int t = 0; t < NT; ++t) {
    const int cur = t & 1, nxt = cur ^ 1;
    const __bf16* Ah = &lds[cur][0][wr][0];
    const __bf16* Bh = &lds[cur][1][wc >> 1][0];

    // ---- phase 0: read A0 (m0-3), B0 (n0-1); stage (t+1) B-h0 -> nxt
#pragma unroll
    for (int m = 0; m < 4; ++m) {
      const __bf16* p = Ah + (m * 16 + l15) * 64;
      a0[m][0] = *(const bf16x8*)(p + kxa);
      a0[m][1] = *(const bf16x8*)(p + kxb);
    }
#pragma unroll
    for (int n = 0; n < 2; ++n) {
      const __bf16* p = Bh + (bro + n * 16 + l15) * 64;
      b0[n][0] = *(const bf16x8*)(p + kxa);
      b0[n][1] = *(const bf16x8*)(p + kxb);
    }
    if (t + 1 < NT) stage_half(Bblk, 0, lda, (t + 1) * 64, &lds[nxt][1][0][0], tid);
    __builtin_amdgcn_s_barrier();
    __builtin_amdgcn_s_setprio(1);
#pragma unroll
    for (int m = 0; m < 4; ++m)
#pragma unroll
      for (int n = 0; n < 2; ++n) {
        acc[m][n] = MFMA(a0[m][0], b0[n][0], acc[m][n], 0, 0, 0);
        acc[m][n] = MFMA(a0[m][1], b0[n][1], acc[m][n], 0, 0, 0);
      }
    __builtin_amdgcn_s_setprio(0);
    __builtin_amdgcn_s_barrier();

    // ---- phase 1: read A1 (m4-7); stage (t+1) B-h1 -> nxt
#pragma unroll
    for (int m = 0; m < 4; ++m) {
      const __bf16* p = Ah + ((m + 4) * 16 + l15) * 64;
      a1[m][0] = *(const bf16x8*)(p + kxa);
      a1[m][1] = *(const bf16x8*)(p + kxb);
    }
    if (t + 1 < NT) stage_half(Bblk, 128, lda, (t + 1) * 64, &lds[nxt][1][1][0], tid);
    __builtin_amdgcn_s_barrier();
    __builtin_amdgcn_s_setprio(1);
#pragma unroll
    for (int m = 0; m < 4; ++m)
#pragma unroll
      for (int n = 0; n < 2; ++n) {
        acc[m + 4][n] = MFMA(a1[m][0], b0[n][0], acc[m + 4][n], 0, 0, 0);
        acc[m + 4][n] = MFMA(a1[m][1], b0[n][1], acc[m + 4][n], 0, 0, 0);
      }
    __builtin_amdgcn_s_setprio(0);
    __builtin_amdgcn_s_barrier();

    // ---- phase 2: read B1 (n2-3); stage (t+2) A-h0 -> cur
#pragma unroll
    for (int n = 0; n < 2; ++n) {
      const __bf16* p = Bh + (bro + (n + 2) * 16 + l15) * 64;
      b1[n][0] = *(const bf16x8*)(p + kxa);
      b1[n][1] = *(const bf16x8*)(p + kxb);
    }
    if (t + 2 < NT) stage_half(Ablk, 0, lda, (t + 2) * 64, &lds[cur][0][0][0], tid);
    __builtin_amdgcn_s_barrier();
    __builtin_amdgcn_s_setprio(1);
#pragma unroll
    for (int m = 0; m < 4; ++m)
#pragma unroll
      for (int n = 0; n < 2; ++n) {
        acc[m + 4][n + 2] = MFMA(a1[m][0], b1[n][0], acc[m + 4][n + 2], 0, 0, 0);
        acc[m + 4][n + 2] = MFMA(a1[m][1], b1[n][1], acc[m + 4][n + 2], 0, 0, 0);
      }
    __builtin_amdgcn_s_setprio(0);
    __builtin_amdgcn_s_barrier();

    // ---- phase 3: stage (t+2) A-h1 -> cur; counted vmcnt (never 0 mid-loop)
    if (t + 2 < NT) {
      stage_half(Ablk, 128, lda, (t + 2) * 64, &lds[cur][0][1][0], tid);
      asm volatile("s_waitcnt vmcnt(4)" ::: "memory");
    } else {
      asm volatile("s_waitcnt vmcnt(0)" ::: "memory");
    }
    __builtin_amdgcn_s_barrier();
    __builtin_amdgcn_s_setprio(1);
#pragma unroll
    for (int m = 0; m < 4; ++m)
#pragma unroll
      for (int n = 0; n < 2; ++n) {
        acc[m][n + 2] = MFMA(a0[m][0], b1[n][0], acc[m][n + 2], 0, 0, 0);
        acc[m][n + 2] = MFMA(a0[m][1], b1[n][1], acc[m][n + 2], 0, 0, 0);
      }
    __builtin_amdgcn_s_setprio(0);
    __builtin_amdgcn_s_barrier();
  }

#pragma unroll
  for (int m = 0; m < 8; ++m)
#pragma unroll
    for (int n = 0; n < 4; ++n)
#pragma unroll
      for (int r = 0; r < 4; ++r) {
        int row = row0 + wr * 128 + m * 16 + lg * 4 + r;
        int col = col0 + wc * 64 + n * 16 + l15;
        Cs[(size_t)row * ldc + col] = (CT)acc[m][n][r];
      }
}

// ---------------- flash attention ----------------
// grid = (32 q-tiles of 64, 16 q-heads), 256 threads (4 waves x 16 q-rows).
// q/k live in the fused qkv buffer (ld 8192). vt: (2048, T) = V^T per head.
__global__ __launch_bounds__(256, 2) void attn_kernel(
    const __bf16* __restrict__ q, const __bf16* __restrict__ k,
    const __bf16* __restrict__ vt, __bf16* __restrict__ o) {
  __shared__ __bf16 Klds[64][264];   // keys x d, +8 pad
  __shared__ __bf16 Vlds[256][72];   // d x keys, +8 pad
  __shared__ __bf16 Plds[4][16][72]; // per-wave P round-trip

  const int tid = threadIdx.x;
  const int wave = tid >> 6;
  const int lane = tid & 63;
  const int l16 = lane & 15;
  const int lg = lane >> 4;
  const int qh = blockIdx.y;
  const int h = qh >> 1;
  const int q0 = blockIdx.x << 6;
  const int qr = q0 + wave * 16;

  bf16x8 qf[8];
  {
    const __bf16* qp = q + (size_t)(qr + l16) * QKVN + qh * DH + lg * 8;
#pragma unroll
    for (int ds = 0; ds < 8; ++ds)
      qf[ds] = *reinterpret_cast<const bf16x8*>(qp + ds * 32);
  }

  f32x4 accO[16] = {};
  float m_run[4] = {-1e30f, -1e30f, -1e30f, -1e30f};
  float l_run[4] = {0.f, 0.f, 0.f, 0.f};

  int t_lo = q0 - (WIN - 1);
  if (t_lo < 0) t_lo = 0;
  t_lo &= ~63;

  for (int t0 = t_lo; t0 <= q0; t0 += 64) {
    __syncthreads();
    {
      const __bf16* kg = k + (size_t)t0 * QKVN + h * DH;
#pragma unroll
      for (int it = 0; it < 8; ++it) {
        int c = tid + it * 256;
        int row = c >> 5, col = (c & 31) * 8;
        *reinterpret_cast<bf16x8*>(&Klds[row][col]) =
            *reinterpret_cast<const bf16x8*>(kg + (size_t)row * QKVN + col);
      }
      const __bf16* vg = vt + (size_t)(h * DH) * TSEQ + t0;
#pragma unroll
      for (int it = 0; it < 8; ++it) {
        int c = tid + it * 256;
        int row = c >> 3, col = (c & 7) * 8;
        *reinterpret_cast<bf16x8*>(&Vlds[row][col]) =
            *reinterpret_cast<const bf16x8*>(vg + (size_t)row * TSEQ + col);
      }
    }
    __syncthreads();

    f32x4 accS[4] = {};
#pragma unroll
    for (int nt = 0; nt < 4; ++nt)
#pragma unroll
      for (int ds = 0; ds < 8; ++ds) {
        bf16x8 kf = *reinterpret_cast<const bf16x8*>(&Klds[nt * 16 + l16][ds * 32 + lg * 8]);
        accS[nt] = MFMA(qf[ds], kf, accS[nt], 0, 0, 0);
      }

    float pv[4][4];
    float mt[4] = {-1e30f, -1e30f, -1e30f, -1e30f};
#pragma unroll
    for (int nt = 0; nt < 4; ++nt) {
      int key = t0 + nt * 16 + l16;
#pragma unroll
      for (int r = 0; r < 4; ++r) {
        int row = qr + lg * 4 + r;
        float s = 50.f * tanhf(accS[nt][r] * 0.02f);
        bool valid = (key <= row) && (row - key < WIN);
        s = valid ? s : -1e30f;
        pv[nt][r] = s;
        mt[r] = fmaxf(mt[r], s);
      }
    }
#pragma unroll
    for (int off = 1; off < 16; off <<= 1)
#pragma unroll
      for (int r = 0; r < 4; ++r)
        mt[r] = fmaxf(mt[r], __shfl_xor(mt[r], off));

    float rs[4];
#pragma unroll
    for (int r = 0; r < 4; ++r) {
      float mn = fmaxf(m_run[r], mt[r]);
      float sc = __expf(m_run[r] - mn);
      m_run[r] = mn;
      l_run[r] *= sc;
      float s0 = 0.f;
#pragma unroll
      for (int nt = 0; nt < 4; ++nt) {
        float p = (pv[nt][r] > -1e29f) ? __expf(pv[nt][r] - mn) : 0.f;
        pv[nt][r] = p;
        s0 += p;
      }
      rs[r] = s0;
#pragma unroll
      for (int nt2 = 0; nt2 < 16; ++nt2)
        accO[nt2][r] *= sc;
    }
#pragma unroll
    for (int off = 1; off < 16; off <<= 1)
#pragma unroll
      for (int r = 0; r < 4; ++r)
        rs[r] += __shfl_xor(rs[r], off);
#pragma unroll
    for (int r = 0; r < 4; ++r)
      l_run[r] += rs[r];

#pragma unroll
    for (int nt = 0; nt < 4; ++nt)
#pragma unroll
      for (int r = 0; r < 4; ++r)
        Plds[wave][lg * 4 + r][nt * 16 + l16] = (__bf16)pv[nt][r];

#pragma unroll
    for (int ks = 0; ks < 2; ++ks) {
      bf16x8 pa = *reinterpret_cast<const bf16x8*>(&Plds[wave][l16][ks * 32 + lg * 8]);
#pragma unroll
      for (int nt2 = 0; nt2 < 16; ++nt2) {
        bf16x8 vb = *reinterpret_cast<const bf16x8*>(&Vlds[nt2 * 16 + l16][ks * 32 + lg * 8]);
        accO[nt2] = MFMA(pa, vb, accO[nt2], 0, 0, 0);
      }
    }
  }

#pragma unroll
  for (int r = 0; r < 4; ++r) {
    float inv_l = 1.f / l_run[r];
    int row = qr + lg * 4 + r;
#pragma unroll
    for (int nt2 = 0; nt2 < 16; ++nt2)
      o[(size_t)row * QKD + qh * DH + nt2 * 16 + l16] = (__bf16)(accO[nt2][r] * inv_l);
  }
}

// ---------------- launcher ----------------

extern "C" void kernel_launch(void* const* d_in, const int* in_sizes, int n_in,
                              void* d_out, int out_size, void* d_ws, size_t ws_size,
                              hipStream_t stream) {
  const float* hs = (const float*)d_in[0];
  const float* Wq = (const float*)d_in[1];
  const float* Wk = (const float*)d_in[2];
  const float* Wv = (const float*)d_in[3];
  const float* Wo = (const float*)d_in[4];
  const int* positions = (const int*)d_in[5];
  float* out = (float*)d_out;

  char* ws = (char*)d_ws;
  const size_t SZ_HS  = (size_t)TSEQ * HDIM * 2;
  const size_t SZ_WQT = (size_t)QKD * HDIM * 2;
  const size_t SZ_WKT = (size_t)KVD * HDIM * 2;
  const size_t SZ_WOT = (size_t)HDIM * QKD * 2;
  const size_t SZ_QKV = (size_t)TSEQ * QKVN * 2;
  const size_t SZ_O   = (size_t)TSEQ * QKD * 2;
  const size_t SZ_TBL = (size_t)TSEQ * 128 * 4;

  __bf16* hs_bf = (__bf16*)ws; ws += SZ_HS;
  __bf16* WqT   = (__bf16*)ws; ws += SZ_WQT;   // WqT/WkT/WvT contiguous -> fused B (8192 x 3584)
  __bf16* WkT   = (__bf16*)ws; ws += SZ_WKT;
  __bf16* WvT   = (__bf16*)ws; ws += SZ_WKT;
  __bf16* WoT   = (__bf16*)ws; ws += SZ_WOT;
  __bf16* qkv   = (__bf16*)ws; ws += SZ_QKV;
  __bf16* o_bf  = (__bf16*)ws; ws += SZ_O;
  float*  cost  = (float*)ws;  ws += SZ_TBL;
  float*  sint  = (float*)ws;  ws += SZ_TBL;
  __bf16* vt_bf = hs_bf;          // overlay: hs_bf dead after QKV GEMM
  float* cpart = (float*)WqT;     // overlay: W{q,k,v}T (58.72MB) dead after QKV GEMM;
                                  // split-K partials = 2*2048*3584*4 = 58.72MB
  if ((size_t)(ws - (char*)d_ws) > ws_size) return;

  // prep
  cvt_bf16_kernel<<<(TSEQ * HDIM) / 1024, 256, 0, stream>>>(hs, hs_bf, (long)TSEQ * HDIM);
  transpose_cvt_kernel<<<dim3(QKD / 32, HDIM / 32), dim3(32, 8), 0, stream>>>(Wq, WqT, HDIM, QKD);
  transpose_cvt_kernel<<<dim3(KVD / 32, HDIM / 32), dim3(32, 8), 0, stream>>>(Wk, WkT, HDIM, KVD);
  transpose_cvt_kernel<<<dim3(KVD / 32, HDIM / 32), dim3(32, 8), 0, stream>>>(Wv, WvT, HDIM, KVD);
  transpose_cvt_kernel<<<dim3(HDIM / 32, QKD / 32), dim3(32, 8), 0, stream>>>(Wo, WoT, QKD, HDIM);
  rope_table_kernel<<<(TSEQ * 128) / 256, 256, 0, stream>>>(positions, cost, sint);

  // fused QKV projection: M=2048, N=8192, K=3584 -> 256 blocks (1/CU)
  gemm256_kernel<__bf16><<<256, 512, 0, stream>>>(hs_bf, WqT, qkv, HDIM, HDIM, QKVN, 256, 0);

  // RoPE (+ q scale 1/16), V transpose (into hs_bf overlay)
  rope_apply_kernel<<<(TSEQ * NQH * 128) / 256, 256, 0, stream>>>(qkv, cost, sint, NQH, QKVN, 0.0625f, TSEQ * NQH * 128);
  rope_apply_kernel<<<(TSEQ * NKVH * 128) / 256, 256, 0, stream>>>(qkv + QKD, cost, sint, NKVH, QKVN, 1.0f, TSEQ * NKVH * 128);
  transpose_bf16_kernel<<<dim3(KVD / 32, TSEQ / 32), dim3(32, 8), 0, stream>>>(qkv + QKD + KVD, vt_bf, QKVN, TSEQ);

  // attention
  attn_kernel<<<dim3(TSEQ / 64, NQH), 256, 0, stream>>>(qkv, qkv + QKD, vt_bf, o_bf);

  // output projection: M=2048, N=3584, K=4096, split-K=2 -> 224 blocks
  gemm256_kernel<float><<<224, 512, 0, stream>>>(o_bf, WoT, cpart, QKD, QKD / 2, HDIM, 112,
                                                 (size_t)TSEQ * HDIM);
  reduce2_kernel<<<1792, 256, 0, stream>>>(cpart, cpart + (size_t)TSEQ * HDIM, out,
                                           TSEQ * HDIM / 4);
}

// Round 4
// 354.875 us; speedup vs baseline: 1.1536x; 1.0048x over previous
//
#include <hip/hip_runtime.h>
#include <math.h>

typedef __attribute__((ext_vector_type(8))) __bf16 bf16x8;
typedef __attribute__((ext_vector_type(4))) __bf16 bf16x4;
typedef __attribute__((ext_vector_type(4))) float f32x4;

#define TSEQ 2048
#define HDIM 3584
#define NQH  16
#define NKVH 8
#define DH   256
#define WIN  1024
#define QKD  (NQH * DH)   /* 4096 */
#define KVD  (NKVH * DH)  /* 2048 */
#define QKVN 8192         /* fused QKV output width */

#define MFMA __builtin_amdgcn_mfma_f32_16x16x32_bf16

__device__ __forceinline__ void gload_lds16(const void* g, void* l) {
  __builtin_amdgcn_global_load_lds(
      (const __attribute__((address_space(1))) void*)g,
      (__attribute__((address_space(3))) void*)l, 16, 0, 0);
}

// ---------------- prep kernels ----------------

__global__ void cvt_bf16_kernel(const float* __restrict__ in,
                                __bf16* __restrict__ out, long n) {
  long i = ((long)blockIdx.x * blockDim.x + threadIdx.x) * 4;
  if (i >= n) return;
  float4 v = *reinterpret_cast<const float4*>(in + i);
  bf16x4 o4;
  o4.x = (__bf16)v.x; o4.y = (__bf16)v.y; o4.z = (__bf16)v.z; o4.w = (__bf16)v.w;
  *reinterpret_cast<bf16x4*>(out + i) = o4;
}

// in: R x C fp32 (row-major)  ->  out: C x R bf16 (row-major)
__global__ void transpose_cvt_kernel(const float* __restrict__ in,
                                     __bf16* __restrict__ out, int R, int C) {
  __shared__ float tile[32][33];
  const int tx = threadIdx.x, ty = threadIdx.y;
  const int c0 = blockIdx.x * 32, r0 = blockIdx.y * 32;
#pragma unroll
  for (int i = 0; i < 4; ++i)
    tile[ty + i * 8][tx] = in[(size_t)(r0 + ty + i * 8) * C + (c0 + tx)];
  __syncthreads();
#pragma unroll
  for (int i = 0; i < 4; ++i)
    out[(size_t)(c0 + ty + i * 8) * R + (r0 + tx)] = (__bf16)tile[tx][ty + i * 8];
}

// in: R x C bf16 (leading dim ldin) -> out: C x R bf16 (leading dim ldout)
__global__ void transpose_bf16_kernel(const __bf16* __restrict__ in,
                                      __bf16* __restrict__ out, int ldin, int ldout) {
  __shared__ __bf16 tile[32][33];
  const int tx = threadIdx.x, ty = threadIdx.y;
  const int c0 = blockIdx.x * 32, r0 = blockIdx.y * 32;
#pragma unroll
  for (int i = 0; i < 4; ++i)
    tile[ty + i * 8][tx] = in[(size_t)(r0 + ty + i * 8) * ldin + (c0 + tx)];
  __syncthreads();
#pragma unroll
  for (int i = 0; i < 4; ++i)
    out[(size_t)(c0 + ty + i * 8) * ldout + (r0 + tx)] = tile[tx][ty + i * 8];
}

__global__ void rope_table_kernel(const int* __restrict__ positions,
                                  float* __restrict__ ct,
                                  float* __restrict__ st) {
  int i = blockIdx.x * blockDim.x + threadIdx.x;
  if (i >= TSEQ * 128) return;
  int t = i >> 7, j = i & 127;
  float invf = (float)exp((double)(-2 * j) * (9.210340371976184 / 256.0));
  float ang = (float)positions[t] * invf;
  ct[i] = cosf(ang);
  st[i] = sinf(ang);
}

// in-place RoPE on bf16 rows of leading-dim ld; also applies `scale`
__global__ void rope_apply_kernel(__bf16* __restrict__ x,
                                  const float* __restrict__ ct,
                                  const float* __restrict__ st,
                                  int heads, int ld, float scale, int total) {
  int i = blockIdx.x * blockDim.x + threadIdx.x;
  if (i >= total) return;
  int j = i & 127;
  int th = i >> 7;
  int t = th / heads;
  int head = th - t * heads;
  size_t base = (size_t)t * ld + head * DH + j;
  float x1 = (float)x[base], x2 = (float)x[base + 128];
  float c = ct[(t << 7) + j], s = st[(t << 7) + j];
  x[base]       = (__bf16)((x1 * c - x2 * s) * scale);
  x[base + 128] = (__bf16)((x2 * c + x1 * s) * scale);
}

// split-K reduce: out[i] = p0[i] + p1[i]  (fp32, float4-vectorized)
__global__ void reduce2_kernel(const float* __restrict__ p0,
                               const float* __restrict__ p1,
                               float* __restrict__ out, int n4) {
  int stride = gridDim.x * blockDim.x;
  for (int i = blockIdx.x * blockDim.x + threadIdx.x; i < n4; i += stride) {
    float4 a = reinterpret_cast<const float4*>(p0)[i];
    float4 b = reinterpret_cast<const float4*>(p1)[i];
    a.x += b.x; a.y += b.y; a.z += b.z; a.w += b.w;
    reinterpret_cast<float4*>(out)[i] = a;
  }
}

// ---------------- 256x256 2-barrier GEMM (split-K capable) ----------------
// A: M x K bf16 (ld lda). B: N x K bf16 (ld lda). C[m][n] = sum_k over slice.
// 512 threads = 8 waves (2Mx4N). BK=64. LDS swizzle: kbyte ^= (row&7)<<4,
// pre-swizzled global source (linear LDS dest) + swizzled ds_read.
// Per K-tile: all 24 ds_reads up front -> stage B(t+1)->nxt -> lgkmcnt(0)
// -> barrier -> stage A(t+2)->cur -> 64-MFMA cluster -> vmcnt(4) -> barrier.

__device__ __forceinline__ void stage_half(const __bf16* __restrict__ gbase,
                                           int row0, int ldg, int k0,
                                           __bf16* lds_half, int tid) {
  const int lane = tid & 63;
  const int w = tid >> 6;
  const int lr = lane >> 3;                    // row&7 within half
  const int swzcol = ((lane & 7) ^ lr) << 3;   // pre-swizzled source column
  const __bf16* g = gbase + (size_t)(row0 + w * 8 + lr) * ldg + k0 + swzcol;
  __bf16* l = lds_half + w * 512;              // wave-uniform dest (elements)
  gload_lds16(g, l);
  gload_lds16(g + (size_t)64 * ldg, l + 4096);
}

template <typename CT>
__global__ __launch_bounds__(512, 2) void gemm256_kernel(
    const __bf16* __restrict__ A, const __bf16* __restrict__ B,
    CT* __restrict__ C, int lda, int Klen, int ldc, int nrc, size_t cstride) {
  __shared__ __bf16 lds[2][2][2][8192];  // [buf][A=0/B=1][half][128*64]

  const int nwg = gridDim.x;
  const int per = nwg >> 3;
  const int wg = (blockIdx.x & 7) * per + (blockIdx.x >> 3);  // XCD chunk swizzle
  const int kslice = wg / nrc;
  const int rem = wg - kslice * nrc;
  const int row0 = (rem & 7) * 256;        // col-major decode: XCD owns col-band
  const int col0 = (rem >> 3) * 256;
  const int k0 = kslice * Klen;
  CT* Cs = C + (size_t)kslice * cstride;

  const int tid = threadIdx.x;
  const int lane = tid & 63, w = tid >> 6;
  const int wr = w >> 2, wc = w & 3;
  const int l15 = lane & 15, lg = lane >> 4;
  const int swz = (lane & 7) << 3;
  const int kxa = (lg * 8) ^ swz;        // ksub 0
  const int kxb = (32 + lg * 8) ^ swz;   // ksub 1
  const int bro = (wc & 1) * 64;

  const __bf16* Ablk = A + (size_t)row0 * lda + k0;
  const __bf16* Bblk = B + (size_t)col0 * lda + k0;

  f32x4 acc[8][4] = {};
  const int NT = Klen >> 6;

  // prologue: tile0 A+B -> buf0; tile1 A -> buf1
  stage_half(Ablk, 0,   lda, 0,  &lds[0][0][0][0], tid);
  stage_half(Ablk, 128, lda, 0,  &lds[0][0][1][0], tid);
  stage_half(Bblk, 0,   lda, 0,  &lds[0][1][0][0], tid);
  stage_half(Bblk, 128, lda, 0,  &lds[0][1][1][0], tid);
  stage_half(Ablk, 0,   lda, 64, &lds[1][0][0][0], tid);
  stage_half(Ablk, 128, lda, 64, &lds[1][0][1][0], tid);
  asm volatile("s_waitcnt vmcnt(4)" ::: "memory");
  __builtin_amdgcn_s_barrier();

  for (int t = 0; t < NT; ++t) {
    const int cur = t & 1, nxt = cur ^ 1;
    const __bf16* Ah = &lds[cur][0][wr][0];
    const __bf16* Bh = &lds[cur][1][wc >> 1][0];

    // all 24 ds_read_b128 up front
    bf16x8 a[8][2], b[4][2];
#pragma unroll
    for (int m = 0; m < 8; ++m) {
      const __bf16* p = Ah + (m * 16 + l15) * 64;
      a[m][0] = *(const bf16x8*)(p + kxa);
      a[m][1] = *(const bf16x8*)(p + kxb);
    }
#pragma unroll
    for (int n = 0; n < 4; ++n) {
      const __bf16* p = Bh + (bro + n * 16 + l15) * 64;
      b[n][0] = *(const bf16x8*)(p + kxa);
      b[n][1] = *(const bf16x8*)(p + kxb);
    }

    // stage next tile's B into nxt (read last in iter t-1, already drained)
    if (t + 1 < NT) {
      stage_half(Bblk, 0,   lda, (t + 1) * 64, &lds[nxt][1][0][0], tid);
      stage_half(Bblk, 128, lda, (t + 1) * 64, &lds[nxt][1][1][0], tid);
    }

    // own reads retired -> barrier -> cur's A region is safe to overwrite
    asm volatile("s_waitcnt lgkmcnt(0)" ::: "memory");
    __builtin_amdgcn_s_barrier();
    if (t + 2 < NT) {
      stage_half(Ablk, 0,   lda, (t + 2) * 64, &lds[cur][0][0][0], tid);
      stage_half(Ablk, 128, lda, (t + 2) * 64, &lds[cur][0][1][0], tid);
    }

    __builtin_amdgcn_s_setprio(1);
#pragma unroll
    for (int m = 0; m < 8; ++m)
#pragma unroll
      for (int n = 0; n < 4; ++n) {
        acc[m][n] = MFMA(a[m][0], b[n][0], acc[m][n], 0, 0, 0);
        acc[m][n] = MFMA(a[m][1], b[n][1], acc[m][n], 0, 0, 0);
      }
    __builtin_amdgcn_s_setprio(0);

    // counted vmcnt: keep A(t+2)'s 4 loads in flight; all older are landed
    if (t + 2 < NT) {
      asm volatile("s_waitcnt vmcnt(4)" ::: "memory");
    } else {
      asm volatile("s_waitcnt vmcnt(0)" ::: "memory");
    }
    __builtin_amdgcn_s_barrier();
  }

#pragma unroll
  for (int m = 0; m < 8; ++m)
#pragma unroll
    for (int n = 0; n < 4; ++n)
#pragma unroll
      for (int r = 0; r < 4; ++r) {
        int row = row0 + wr * 128 + m * 16 + lg * 4 + r;
        int col = col0 + wc * 64 + n * 16 + l15;
        Cs[(size_t)row * ldc + col] = (CT)acc[m][n][r];
      }
}

// ---------------- flash attention ----------------
// grid = (32 q-tiles of 64, 16 q-heads), 256 threads (4 waves x 16 q-rows).
// q/k live in the fused qkv buffer (ld 8192). vt: (2048, T) = V^T per head.
__global__ __launch_bounds__(256, 2) void attn_kernel(
    const __bf16* __restrict__ q, const __bf16* __restrict__ k,
    const __bf16* __restrict__ vt, __bf16* __restrict__ o) {
  __shared__ __bf16 Klds[64][264];   // keys x d, +8 pad
  __shared__ __bf16 Vlds[256][72];   // d x keys, +8 pad
  __shared__ __bf16 Plds[4][16][72]; // per-wave P round-trip

  const int tid = threadIdx.x;
  const int wave = tid >> 6;
  const int lane = tid & 63;
  const int l16 = lane & 15;
  const int lg = lane >> 4;
  const int qh = blockIdx.y;
  const int h = qh >> 1;
  const int q0 = blockIdx.x << 6;
  const int qr = q0 + wave * 16;

  bf16x8 qf[8];
  {
    const __bf16* qp = q + (size_t)(qr + l16) * QKVN + qh * DH + lg * 8;
#pragma unroll
    for (int ds = 0; ds < 8; ++ds)
      qf[ds] = *reinterpret_cast<const bf16x8*>(qp + ds * 32);
  }

  f32x4 accO[16] = {};
  float m_run[4] = {-1e30f, -1e30f, -1e30f, -1e30f};
  float l_run[4] = {0.f, 0.f, 0.f, 0.f};

  int t_lo = q0 - (WIN - 1);
  if (t_lo < 0) t_lo = 0;
  t_lo &= ~63;

  for (int t0 = t_lo; t0 <= q0; t0 += 64) {
    __syncthreads();
    {
      const __bf16* kg = k + (size_t)t0 * QKVN + h * DH;
#pragma unroll
      for (int it = 0; it < 8; ++it) {
        int c = tid + it * 256;
        int row = c >> 5, col = (c & 31) * 8;
        *reinterpret_cast<bf16x8*>(&Klds[row][col]) =
            *reinterpret_cast<const bf16x8*>(kg + (size_t)row * QKVN + col);
      }
      const __bf16* vg = vt + (size_t)(h * DH) * TSEQ + t0;
#pragma unroll
      for (int it = 0; it < 8; ++it) {
        int c = tid + it * 256;
        int row = c >> 3, col = (c & 7) * 8;
        *reinterpret_cast<bf16x8*>(&Vlds[row][col]) =
            *reinterpret_cast<const bf16x8*>(vg + (size_t)row * TSEQ + col);
      }
    }
    __syncthreads();

    f32x4 accS[4] = {};
#pragma unroll
    for (int nt = 0; nt < 4; ++nt)
#pragma unroll
      for (int ds = 0; ds < 8; ++ds) {
        bf16x8 kf = *reinterpret_cast<const bf16x8*>(&Klds[nt * 16 + l16][ds * 32 + lg * 8]);
        accS[nt] = MFMA(qf[ds], kf, accS[nt], 0, 0, 0);
      }

    float pv[4][4];
    float mt[4] = {-1e30f, -1e30f, -1e30f, -1e30f};
#pragma unroll
    for (int nt = 0; nt < 4; ++nt) {
      int key = t0 + nt * 16 + l16;
#pragma unroll
      for (int r = 0; r < 4; ++r) {
        int row = qr + lg * 4 + r;
        float s = 50.f * tanhf(accS[nt][r] * 0.02f);
        bool valid = (key <= row) && (row - key < WIN);
        s = valid ? s : -1e30f;
        pv[nt][r] = s;
        mt[r] = fmaxf(mt[r], s);
      }
    }
#pragma unroll
    for (int off = 1; off < 16; off <<= 1)
#pragma unroll
      for (int r = 0; r < 4; ++r)
        mt[r] = fmaxf(mt[r], __shfl_xor(mt[r], off));

    float rs[4];
#pragma unroll
    for (int r = 0; r < 4; ++r) {
      float mn = fmaxf(m_run[r], mt[r]);
      float sc = __expf(m_run[r] - mn);
      m_run[r] = mn;
      l_run[r] *= sc;
      float s0 = 0.f;
#pragma unroll
      for (int nt = 0; nt < 4; ++nt) {
        float p = (pv[nt][r] > -1e29f) ? __expf(pv[nt][r] - mn) : 0.f;
        pv[nt][r] = p;
        s0 += p;
      }
      rs[r] = s0;
#pragma unroll
      for (int nt2 = 0; nt2 < 16; ++nt2)
        accO[nt2][r] *= sc;
    }
#pragma unroll
    for (int off = 1; off < 16; off <<= 1)
#pragma unroll
      for (int r = 0; r < 4; ++r)
        rs[r] += __shfl_xor(rs[r], off);
#pragma unroll
    for (int r = 0; r < 4; ++r)
      l_run[r] += rs[r];

#pragma unroll
    for (int nt = 0; nt < 4; ++nt)
#pragma unroll
      for (int r = 0; r < 4; ++r)
        Plds[wave][lg * 4 + r][nt * 16 + l16] = (__bf16)pv[nt][r];

#pragma unroll
    for (int ks = 0; ks < 2; ++ks) {
      bf16x8 pa = *reinterpret_cast<const bf16x8*>(&Plds[wave][l16][ks * 32 + lg * 8]);
#pragma unroll
      for (int nt2 = 0; nt2 < 16; ++nt2) {
        bf16x8 vb = *reinterpret_cast<const bf16x8*>(&Vlds[nt2 * 16 + l16][ks * 32 + lg * 8]);
        accO[nt2] = MFMA(pa, vb, accO[nt2], 0, 0, 0);
      }
    }
  }

#pragma unroll
  for (int r = 0; r < 4; ++r) {
    float inv_l = 1.f / l_run[r];
    int row = qr + lg * 4 + r;
#pragma unroll
    for (int nt2 = 0; nt2 < 16; ++nt2)
      o[(size_t)row * QKD + qh * DH + nt2 * 16 + l16] = (__bf16)(accO[nt2][r] * inv_l);
  }
}

// ---------------- launcher ----------------

extern "C" void kernel_launch(void* const* d_in, const int* in_sizes, int n_in,
                              void* d_out, int out_size, void* d_ws, size_t ws_size,
                              hipStream_t stream) {
  const float* hs = (const float*)d_in[0];
  const float* Wq = (const float*)d_in[1];
  const float* Wk = (const float*)d_in[2];
  const float* Wv = (const float*)d_in[3];
  const float* Wo = (const float*)d_in[4];
  const int* positions = (const int*)d_in[5];
  float* out = (float*)d_out;

  char* ws = (char*)d_ws;
  const size_t SZ_HS  = (size_t)TSEQ * HDIM * 2;
  const size_t SZ_WQT = (size_t)QKD * HDIM * 2;
  const size_t SZ_WKT = (size_t)KVD * HDIM * 2;
  const size_t SZ_WOT = (size_t)HDIM * QKD * 2;
  const size_t SZ_QKV = (size_t)TSEQ * QKVN * 2;
  const size_t SZ_O   = (size_t)TSEQ * QKD * 2;
  const size_t SZ_TBL = (size_t)TSEQ * 128 * 4;

  __bf16* hs_bf = (__bf16*)ws; ws += SZ_HS;
  __bf16* WqT   = (__bf16*)ws; ws += SZ_WQT;   // WqT/WkT/WvT contiguous -> fused B (8192 x 3584)
  __bf16* WkT   = (__bf16*)ws; ws += SZ_WKT;
  __bf16* WvT   = (__bf16*)ws; ws += SZ_WKT;
  __bf16* WoT   = (__bf16*)ws; ws += SZ_WOT;
  __bf16* qkv   = (__bf16*)ws; ws += SZ_QKV;
  __bf16* o_bf  = (__bf16*)ws; ws += SZ_O;
  float*  cost  = (float*)ws;  ws += SZ_TBL;
  float*  sint  = (float*)ws;  ws += SZ_TBL;
  __bf16* vt_bf = hs_bf;          // overlay: hs_bf dead after QKV GEMM
  float* cpart = (float*)WqT;     // overlay: W{q,k,v}T (58.72MB) dead after QKV GEMM;
                                  // split-K partials = 2*2048*3584*4 = 58.72MB
  if ((size_t)(ws - (char*)d_ws) > ws_size) return;

  // prep
  cvt_bf16_kernel<<<(TSEQ * HDIM) / 1024, 256, 0, stream>>>(hs, hs_bf, (long)TSEQ * HDIM);
  transpose_cvt_kernel<<<dim3(QKD / 32, HDIM / 32), dim3(32, 8), 0, stream>>>(Wq, WqT, HDIM, QKD);
  transpose_cvt_kernel<<<dim3(KVD / 32, HDIM / 32), dim3(32, 8), 0, stream>>>(Wk, WkT, HDIM, KVD);
  transpose_cvt_kernel<<<dim3(KVD / 32, HDIM / 32), dim3(32, 8), 0, stream>>>(Wv, WvT, HDIM, KVD);
  transpose_cvt_kernel<<<dim3(HDIM / 32, QKD / 32), dim3(32, 8), 0, stream>>>(Wo, WoT, QKD, HDIM);
  rope_table_kernel<<<(TSEQ * 128) / 256, 256, 0, stream>>>(positions, cost, sint);

  // fused QKV projection: M=2048, N=8192, K=3584 -> 256 blocks (1/CU)
  gemm256_kernel<__bf16><<<256, 512, 0, stream>>>(hs_bf, WqT, qkv, HDIM, HDIM, QKVN, 256, 0);

  // RoPE (+ q scale 1/16), V transpose (into hs_bf overlay)
  rope_apply_kernel<<<(TSEQ * NQH * 128) / 256, 256, 0, stream>>>(qkv, cost, sint, NQH, QKVN, 0.0625f, TSEQ * NQH * 128);
  rope_apply_kernel<<<(TSEQ * NKVH * 128) / 256, 256, 0, stream>>>(qkv + QKD, cost, sint, NKVH, QKVN, 1.0f, TSEQ * NKVH * 128);
  transpose_bf16_kernel<<<dim3(KVD / 32, TSEQ / 32), dim3(32, 8), 0, stream>>>(qkv + QKD + KVD, vt_bf, QKVN, TSEQ);

  // attention
  attn_kernel<<<dim3(TSEQ / 64, NQH), 256, 0, stream>>>(qkv, qkv + QKD, vt_bf, o_bf);

  // output projection: M=2048, N=3584, K=4096, split-K=2 -> 224 blocks
  gemm256_kernel<float><<<224, 512, 0, stream>>>(o_bf, WoT, cpart, QKD, QKD / 2, HDIM, 112,
                                                 (size_t)TSEQ * HDIM);
  reduce2_kernel<<<1792, 256, 0, stream>>>(cpart, cpart + (size_t)TSEQ * HDIM, out,
                                           TSEQ * HDIM / 4);
}

// Round 5
// 340.482 us; speedup vs baseline: 1.2024x; 1.0423x over previous
//
#include <hip/hip_runtime.h>
#include <math.h>

typedef __attribute__((ext_vector_type(8))) __bf16 bf16x8;
typedef __attribute__((ext_vector_type(4))) __bf16 bf16x4;
typedef __attribute__((ext_vector_type(4))) float f32x4;

#define TSEQ 2048
#define HDIM 3584
#define NQH  16
#define NKVH 8
#define DH   256
#define WIN  1024
#define QKD  (NQH * DH)   /* 4096 */
#define KVD  (NKVH * DH)  /* 2048 */
#define QKVN 8192         /* fused QKV output width */

#define MFMA __builtin_amdgcn_mfma_f32_16x16x32_bf16

__device__ __forceinline__ void gload_lds16(const void* g, void* l) {
  __builtin_amdgcn_global_load_lds(
      (const __attribute__((address_space(1))) void*)g,
      (__attribute__((address_space(3))) void*)l, 16, 0, 0);
}

// ---------------- prep kernels ----------------

__global__ void cvt_bf16_kernel(const float* __restrict__ in,
                                __bf16* __restrict__ out, long n) {
  long i = ((long)blockIdx.x * blockDim.x + threadIdx.x) * 4;
  if (i >= n) return;
  float4 v = *reinterpret_cast<const float4*>(in + i);
  bf16x4 o4;
  o4.x = (__bf16)v.x; o4.y = (__bf16)v.y; o4.z = (__bf16)v.z; o4.w = (__bf16)v.w;
  *reinterpret_cast<bf16x4*>(out + i) = o4;
}

// in: R x C fp32 (row-major)  ->  out: C x R bf16 (row-major)
__global__ void transpose_cvt_kernel(const float* __restrict__ in,
                                     __bf16* __restrict__ out, int R, int C) {
  __shared__ float tile[32][33];
  const int tx = threadIdx.x, ty = threadIdx.y;
  const int c0 = blockIdx.x * 32, r0 = blockIdx.y * 32;
#pragma unroll
  for (int i = 0; i < 4; ++i)
    tile[ty + i * 8][tx] = in[(size_t)(r0 + ty + i * 8) * C + (c0 + tx)];
  __syncthreads();
#pragma unroll
  for (int i = 0; i < 4; ++i)
    out[(size_t)(c0 + ty + i * 8) * R + (r0 + tx)] = (__bf16)tile[tx][ty + i * 8];
}

// in: R x C bf16 (leading dim ldin) -> out: C x R bf16 (leading dim ldout)
__global__ void transpose_bf16_kernel(const __bf16* __restrict__ in,
                                      __bf16* __restrict__ out, int ldin, int ldout) {
  __shared__ __bf16 tile[32][33];
  const int tx = threadIdx.x, ty = threadIdx.y;
  const int c0 = blockIdx.x * 32, r0 = blockIdx.y * 32;
#pragma unroll
  for (int i = 0; i < 4; ++i)
    tile[ty + i * 8][tx] = in[(size_t)(r0 + ty + i * 8) * ldin + (c0 + tx)];
  __syncthreads();
#pragma unroll
  for (int i = 0; i < 4; ++i)
    out[(size_t)(c0 + ty + i * 8) * ldout + (r0 + tx)] = tile[tx][ty + i * 8];
}

__global__ void rope_table_kernel(const int* __restrict__ positions,
                                  float* __restrict__ ct,
                                  float* __restrict__ st) {
  int i = blockIdx.x * blockDim.x + threadIdx.x;
  if (i >= TSEQ * 128) return;
  int t = i >> 7, j = i & 127;
  float invf = (float)exp((double)(-2 * j) * (9.210340371976184 / 256.0));
  float ang = (float)positions[t] * invf;
  ct[i] = cosf(ang);
  st[i] = sinf(ang);
}

// in-place RoPE on bf16 rows of leading-dim ld; also applies `scale`
__global__ void rope_apply_kernel(__bf16* __restrict__ x,
                                  const float* __restrict__ ct,
                                  const float* __restrict__ st,
                                  int heads, int ld, float scale, int total) {
  int i = blockIdx.x * blockDim.x + threadIdx.x;
  if (i >= total) return;
  int j = i & 127;
  int th = i >> 7;
  int t = th / heads;
  int head = th - t * heads;
  size_t base = (size_t)t * ld + head * DH + j;
  float x1 = (float)x[base], x2 = (float)x[base + 128];
  float c = ct[(t << 7) + j], s = st[(t << 7) + j];
  x[base]       = (__bf16)((x1 * c - x2 * s) * scale);
  x[base + 128] = (__bf16)((x2 * c + x1 * s) * scale);
}

// split-K reduce: out[i] = p0[i] + p1[i]  (fp32, float4-vectorized)
__global__ void reduce2_kernel(const float* __restrict__ p0,
                               const float* __restrict__ p1,
                               float* __restrict__ out, int n4) {
  int stride = gridDim.x * blockDim.x;
  for (int i = blockIdx.x * blockDim.x + threadIdx.x; i < n4; i += stride) {
    float4 a = reinterpret_cast<const float4*>(p0)[i];
    float4 b = reinterpret_cast<const float4*>(p1)[i];
    a.x += b.x; a.y += b.y; a.z += b.z; a.w += b.w;
    reinterpret_cast<float4*>(out)[i] = a;
  }
}

// ---------------- 256x256 8-phase GEMM, 2 K-tiles/iter ----------------
// A: M x K bf16 (ld lda). B: N x K bf16 (ld lda). C[m][n] = sum_k over slice.
// 512 threads = 8 waves (2Mx4N). BK=64. buf0 = even tiles, buf1 = odd tiles.
// Swizzle: byte ^= (row&7)<<4, pre-swizzled global source + swizzled ds_read.
// Stage stream: ph1:B0(o) ph2:B1(o) ph3:A0(e+2) ph4:A1(e+2) ph5:B0(e+2)
// ph6:B1(e+2) ph7:A0(o+2) ph8:A1(o+2); vmcnt(4) at ph4/ph8 only.

__device__ __forceinline__ void stage_half(const __bf16* __restrict__ gbase,
                                           int row0, int ldg, int k0,
                                           __bf16* lds_half, int tid) {
  const int lane = tid & 63;
  const int w = tid >> 6;
  const int lr = lane >> 3;                    // row&7 within half
  const int swzcol = ((lane & 7) ^ lr) << 3;   // pre-swizzled source column
  const __bf16* g = gbase + (size_t)(row0 + w * 8 + lr) * ldg + k0 + swzcol;
  __bf16* l = lds_half + w * 512;              // wave-uniform dest (elements)
  gload_lds16(g, l);
  gload_lds16(g + (size_t)64 * ldg, l + 4096);
}

#define BAR __builtin_amdgcn_s_barrier()

#define RD_A(DST, BASE, MO)                                         \
  _Pragma("unroll")                                                 \
  for (int m_ = 0; m_ < 4; ++m_) {                                  \
    const __bf16* p_ = (BASE) + (((MO) + m_) * 16 + l15) * 64;      \
    DST[m_][0] = *(const bf16x8*)(p_ + kxa);                        \
    DST[m_][1] = *(const bf16x8*)(p_ + kxb);                        \
  }

#define RD_B(DST, BASE, NO)                                         \
  _Pragma("unroll")                                                 \
  for (int n_ = 0; n_ < 2; ++n_) {                                  \
    const __bf16* p_ = (BASE) + (bro + ((NO) + n_) * 16 + l15) * 64;\
    DST[n_][0] = *(const bf16x8*)(p_ + kxa);                        \
    DST[n_][1] = *(const bf16x8*)(p_ + kxb);                        \
  }

#define MQUAD(AF, BF, MO, NO)                                          \
  __builtin_amdgcn_s_setprio(1);                                       \
  _Pragma("unroll")                                                    \
  for (int m_ = 0; m_ < 4; ++m_)                                       \
    _Pragma("unroll")                                                  \
    for (int n_ = 0; n_ < 2; ++n_) {                                   \
      acc[(MO) + m_][(NO) + n_] =                                      \
          MFMA(AF[m_][0], BF[n_][0], acc[(MO) + m_][(NO) + n_], 0, 0, 0); \
      acc[(MO) + m_][(NO) + n_] =                                      \
          MFMA(AF[m_][1], BF[n_][1], acc[(MO) + m_][(NO) + n_], 0, 0, 0); \
    }                                                                  \
  __builtin_amdgcn_s_setprio(0);

template <typename CT>
__global__ __launch_bounds__(512, 2) void gemm256_kernel(
    const __bf16* __restrict__ A, const __bf16* __restrict__ B,
    CT* __restrict__ C, int lda, int Klen, int ldc, int nrc, size_t cstride) {
  __shared__ __bf16 lds[2][2][2][8192];  // [tile-parity][A=0/B=1][half][128*64]

  const int nwg = gridDim.x;
  const int per = nwg >> 3;
  const int wg = (blockIdx.x & 7) * per + (blockIdx.x >> 3);  // XCD chunk swizzle
  const int kslice = wg / nrc;
  const int rem = wg - kslice * nrc;
  const int row0 = (rem & 7) * 256;        // col-major decode: XCD owns col-band
  const int col0 = (rem >> 3) * 256;
  const int k0 = kslice * Klen;
  CT* Cs = C + (size_t)kslice * cstride;

  const int tid = threadIdx.x;
  const int lane = tid & 63, w = tid >> 6;
  const int wr = w >> 2, wc = w & 3;
  const int l15 = lane & 15, lg = lane >> 4;
  const int swz = (lane & 7) << 3;
  const int kxa = (lg * 8) ^ swz;        // ksub 0
  const int kxb = (32 + lg * 8) ^ swz;   // ksub 1
  const int bro = (wc & 1) * 64;

  const __bf16* Ablk = A + (size_t)row0 * lda + k0;
  const __bf16* Bblk = B + (size_t)col0 * lda + k0;

  const __bf16* Ae = &lds[0][0][wr][0];
  const __bf16* Be = &lds[0][1][wc >> 1][0];
  const __bf16* Ao = &lds[1][0][wr][0];
  const __bf16* Bo = &lds[1][1][wc >> 1][0];

  f32x4 acc[8][4] = {};
  const int NT = Klen >> 6;
  const int NI = NT >> 1;

  // prologue: tile0 all halves -> buf0; tile1 A halves -> buf1
  stage_half(Ablk, 0,   lda, 0,  &lds[0][0][0][0], tid);
  stage_half(Ablk, 128, lda, 0,  &lds[0][0][1][0], tid);
  stage_half(Bblk, 0,   lda, 0,  &lds[0][1][0][0], tid);
  stage_half(Bblk, 128, lda, 0,  &lds[0][1][1][0], tid);
  stage_half(Ablk, 0,   lda, 64, &lds[1][0][0][0], tid);
  stage_half(Ablk, 128, lda, 64, &lds[1][0][1][0], tid);
  asm volatile("s_waitcnt vmcnt(4)" ::: "memory");
  BAR;

  bf16x8 a03[4][2], a47[4][2], b01[2][2], b23[2][2];

  for (int j = 0; j < NI; ++j) {
    const int e = 2 * j, o = 2 * j + 1;
    const bool last = (j == NI - 1);

    // ---- ph1: read e.A03 + e.B01; stage B0(o)->buf1
    RD_A(a03, Ae, 0);
    RD_B(b01, Be, 0);
    stage_half(Bblk, 0, lda, o * 64, &lds[1][1][0][0], tid);
    asm volatile("s_waitcnt lgkmcnt(8)" ::: "memory");
    BAR; MQUAD(a03, b01, 0, 0); BAR;

    // ---- ph2: read e.A47; stage B1(o)->buf1
    RD_A(a47, Ae, 4);
    stage_half(Bblk, 128, lda, o * 64, &lds[1][1][1][0], tid);
    BAR; MQUAD(a47, b01, 4, 0); BAR;

    // ---- ph3: read e.B23; stage A0(e+2)->buf0 (buf0.A free after ph2 bar)
    RD_B(b23, Be, 2);
    if (!last) stage_half(Ablk, 0, lda, (e + 2) * 64, &lds[0][0][0][0], tid);
    BAR; MQUAD(a47, b23, 4, 2); BAR;

    // ---- ph4: stage A1(e+2)->buf0; counted vmcnt -> tile o fully landed
    if (!last) {
      stage_half(Ablk, 128, lda, (e + 2) * 64, &lds[0][0][1][0], tid);
      asm volatile("s_waitcnt vmcnt(4)" ::: "memory");
    } else {
      asm volatile("s_waitcnt vmcnt(0)" ::: "memory");
    }
    BAR; MQUAD(a03, b23, 0, 2); BAR;

    // ---- ph5: read o.A03 + o.B01; stage B0(e+2)->buf0 (buf0.B free after ph3)
    RD_A(a03, Ao, 0);
    RD_B(b01, Bo, 0);
    if (!last) stage_half(Bblk, 0, lda, (e + 2) * 64, &lds[0][1][0][0], tid);
    asm volatile("s_waitcnt lgkmcnt(8)" ::: "memory");
    BAR; MQUAD(a03, b01, 0, 0); BAR;

    // ---- ph6: read o.A47; stage B1(e+2)->buf0
    RD_A(a47, Ao, 4);
    if (!last) stage_half(Bblk, 128, lda, (e + 2) * 64, &lds[0][1][1][0], tid);
    BAR; MQUAD(a47, b01, 4, 0); BAR;

    // ---- ph7: read o.B23; stage A0(o+2)->buf1 (buf1.A free after ph6 bar)
    RD_B(b23, Bo, 2);
    if (!last) stage_half(Ablk, 0, lda, (o + 2) * 64, &lds[1][0][0][0], tid);
    BAR; MQUAD(a47, b23, 4, 2); BAR;

    // ---- ph8: stage A1(o+2)->buf1; counted vmcnt -> tile e+2 fully landed
    if (!last) {
      stage_half(Ablk, 128, lda, (o + 2) * 64, &lds[1][0][1][0], tid);
      asm volatile("s_waitcnt vmcnt(4)" ::: "memory");
    }
    BAR; MQUAD(a03, b23, 0, 2); BAR;
  }

#pragma unroll
  for (int m = 0; m < 8; ++m)
#pragma unroll
    for (int n = 0; n < 4; ++n)
#pragma unroll
      for (int r = 0; r < 4; ++r) {
        int row = row0 + wr * 128 + m * 16 + lg * 4 + r;
        int col = col0 + wc * 64 + n * 16 + l15;
        Cs[(size_t)row * ldc + col] = (CT)acc[m][n][r];
      }
}

// ---------------- flash attention (fixed-max softmax) ----------------
// Scores are softcapped to |s|<=50, so exp(s-50) never under/overflows:
// no running max, no rescale. p = exp(50*tanh(x/50)-50) = exp(-100/(e^{.04x}+1)).
// grid = (32 q-tiles of 64, 16 q-heads), 256 threads (4 waves x 16 q-rows).
__global__ __launch_bounds__(256, 2) void attn_kernel(
    const __bf16* __restrict__ q, const __bf16* __restrict__ k,
    const __bf16* __restrict__ vt, __bf16* __restrict__ o) {
  __shared__ __bf16 Klds[64][264];   // keys x d, +8 pad
  __shared__ __bf16 Vlds[256][72];   // d x keys, +8 pad
  __shared__ __bf16 Plds[4][16][72]; // per-wave P round-trip

  const int tid = threadIdx.x;
  const int wave = tid >> 6;
  const int lane = tid & 63;
  const int l16 = lane & 15;
  const int lg = lane >> 4;
  const int qh = blockIdx.y;
  const int h = qh >> 1;
  const int q0 = blockIdx.x << 6;
  const int qr = q0 + wave * 16;

  bf16x8 qf[8];
  {
    const __bf16* qp = q + (size_t)(qr + l16) * QKVN + qh * DH + lg * 8;
#pragma unroll
    for (int ds = 0; ds < 8; ++ds)
      qf[ds] = *reinterpret_cast<const bf16x8*>(qp + ds * 32);
  }

  f32x4 accO[16] = {};
  float l_run[4] = {0.f, 0.f, 0.f, 0.f};

  int t_lo = q0 - (WIN - 1);
  if (t_lo < 0) t_lo = 0;
  t_lo &= ~63;

  for (int t0 = t_lo; t0 <= q0; t0 += 64) {
    __syncthreads();
    {
      const __bf16* kg = k + (size_t)t0 * QKVN + h * DH;
#pragma unroll
      for (int it = 0; it < 8; ++it) {
        int c = tid + it * 256;
        int row = c >> 5, col = (c & 31) * 8;
        *reinterpret_cast<bf16x8*>(&Klds[row][col]) =
            *reinterpret_cast<const bf16x8*>(kg + (size_t)row * QKVN + col);
      }
      const __bf16* vg = vt + (size_t)(h * DH) * TSEQ + t0;
#pragma unroll
      for (int it = 0; it < 8; ++it) {
        int c = tid + it * 256;
        int row = c >> 3, col = (c & 7) * 8;
        *reinterpret_cast<bf16x8*>(&Vlds[row][col]) =
            *reinterpret_cast<const bf16x8*>(vg + (size_t)row * TSEQ + col);
      }
    }
    __syncthreads();

    f32x4 accS[4] = {};
    __builtin_amdgcn_s_setprio(1);
#pragma unroll
    for (int nt = 0; nt < 4; ++nt)
#pragma unroll
      for (int ds = 0; ds < 8; ++ds) {
        bf16x8 kf = *reinterpret_cast<const bf16x8*>(&Klds[nt * 16 + l16][ds * 32 + lg * 8]);
        accS[nt] = MFMA(qf[ds], kf, accS[nt], 0, 0, 0);
      }
    __builtin_amdgcn_s_setprio(0);

    // fused softcap+exp with fixed max=50; p in [0,1]
    float rs[4] = {0.f, 0.f, 0.f, 0.f};
#pragma unroll
    for (int nt = 0; nt < 4; ++nt) {
      int key = t0 + nt * 16 + l16;
#pragma unroll
      for (int r = 0; r < 4; ++r) {
        int row = qr + lg * 4 + r;
        float t = __expf(accS[nt][r] * 0.04f);
        float p = __expf(-100.0f / (t + 1.0f));
        bool valid = (key <= row) && (row - key < WIN);
        p = valid ? p : 0.f;
        rs[r] += p;
        Plds[wave][lg * 4 + r][nt * 16 + l16] = (__bf16)p;
      }
    }
#pragma unroll
    for (int off = 1; off < 16; off <<= 1)
#pragma unroll
      for (int r = 0; r < 4; ++r)
        rs[r] += __shfl_xor(rs[r], off);
#pragma unroll
    for (int r = 0; r < 4; ++r)
      l_run[r] += rs[r];

    __builtin_amdgcn_s_setprio(1);
#pragma unroll
    for (int ks = 0; ks < 2; ++ks) {
      bf16x8 pa = *reinterpret_cast<const bf16x8*>(&Plds[wave][l16][ks * 32 + lg * 8]);
#pragma unroll
      for (int nt2 = 0; nt2 < 16; ++nt2) {
        bf16x8 vb = *reinterpret_cast<const bf16x8*>(&Vlds[nt2 * 16 + l16][ks * 32 + lg * 8]);
        accO[nt2] = MFMA(pa, vb, accO[nt2], 0, 0, 0);
      }
    }
    __builtin_amdgcn_s_setprio(0);
  }

#pragma unroll
  for (int r = 0; r < 4; ++r) {
    float inv_l = 1.f / l_run[r];
    int row = qr + lg * 4 + r;
#pragma unroll
    for (int nt2 = 0; nt2 < 16; ++nt2)
      o[(size_t)row * QKD + qh * DH + nt2 * 16 + l16] = (__bf16)(accO[nt2][r] * inv_l);
  }
}

// ---------------- launcher ----------------

extern "C" void kernel_launch(void* const* d_in, const int* in_sizes, int n_in,
                              void* d_out, int out_size, void* d_ws, size_t ws_size,
                              hipStream_t stream) {
  const float* hs = (const float*)d_in[0];
  const float* Wq = (const float*)d_in[1];
  const float* Wk = (const float*)d_in[2];
  const float* Wv = (const float*)d_in[3];
  const float* Wo = (const float*)d_in[4];
  const int* positions = (const int*)d_in[5];
  float* out = (float*)d_out;

  char* ws = (char*)d_ws;
  const size_t SZ_HS  = (size_t)TSEQ * HDIM * 2;
  const size_t SZ_WQT = (size_t)QKD * HDIM * 2;
  const size_t SZ_WKT = (size_t)KVD * HDIM * 2;
  const size_t SZ_WOT = (size_t)HDIM * QKD * 2;
  const size_t SZ_QKV = (size_t)TSEQ * QKVN * 2;
  const size_t SZ_O   = (size_t)TSEQ * QKD * 2;
  const size_t SZ_TBL = (size_t)TSEQ * 128 * 4;

  __bf16* hs_bf = (__bf16*)ws; ws += SZ_HS;
  __bf16* WqT   = (__bf16*)ws; ws += SZ_WQT;   // WqT/WkT/WvT contiguous -> fused B (8192 x 3584)
  __bf16* WkT   = (__bf16*)ws; ws += SZ_WKT;
  __bf16* WvT   = (__bf16*)ws; ws += SZ_WKT;
  __bf16* WoT   = (__bf16*)ws; ws += SZ_WOT;
  __bf16* qkv   = (__bf16*)ws; ws += SZ_QKV;
  __bf16* o_bf  = (__bf16*)ws; ws += SZ_O;
  float*  cost  = (float*)ws;  ws += SZ_TBL;
  float*  sint  = (float*)ws;  ws += SZ_TBL;
  __bf16* vt_bf = hs_bf;          // overlay: hs_bf dead after QKV GEMM
  float* cpart = (float*)WqT;     // overlay: W{q,k,v}T (58.72MB) dead after QKV GEMM
  if ((size_t)(ws - (char*)d_ws) > ws_size) return;

  // prep
  cvt_bf16_kernel<<<(TSEQ * HDIM) / 1024, 256, 0, stream>>>(hs, hs_bf, (long)TSEQ * HDIM);
  transpose_cvt_kernel<<<dim3(QKD / 32, HDIM / 32), dim3(32, 8), 0, stream>>>(Wq, WqT, HDIM, QKD);
  transpose_cvt_kernel<<<dim3(KVD / 32, HDIM / 32), dim3(32, 8), 0, stream>>>(Wk, WkT, HDIM, KVD);
  transpose_cvt_kernel<<<dim3(KVD / 32, HDIM / 32), dim3(32, 8), 0, stream>>>(Wv, WvT, HDIM, KVD);
  transpose_cvt_kernel<<<dim3(HDIM / 32, QKD / 32), dim3(32, 8), 0, stream>>>(Wo, WoT, QKD, HDIM);
  rope_table_kernel<<<(TSEQ * 128) / 256, 256, 0, stream>>>(positions, cost, sint);

  // fused QKV projection: M=2048, N=8192, K=3584 -> 256 blocks (1/CU)
  gemm256_kernel<__bf16><<<256, 512, 0, stream>>>(hs_bf, WqT, qkv, HDIM, HDIM, QKVN, 256, 0);

  // RoPE (+ q scale 1/16), V transpose (into hs_bf overlay)
  rope_apply_kernel<<<(TSEQ * NQH * 128) / 256, 256, 0, stream>>>(qkv, cost, sint, NQH, QKVN, 0.0625f, TSEQ * NQH * 128);
  rope_apply_kernel<<<(TSEQ * NKVH * 128) / 256, 256, 0, stream>>>(qkv + QKD, cost, sint, NKVH, QKVN, 1.0f, TSEQ * NKVH * 128);
  transpose_bf16_kernel<<<dim3(KVD / 32, TSEQ / 32), dim3(32, 8), 0, stream>>>(qkv + QKD + KVD, vt_bf, QKVN, TSEQ);

  // attention
  attn_kernel<<<dim3(TSEQ / 64, NQH), 256, 0, stream>>>(qkv, qkv + QKD, vt_bf, o_bf);

  // output projection: M=2048, N=3584, K=4096, split-K=2 -> 224 blocks
  gemm256_kernel<float><<<224, 512, 0, stream>>>(o_bf, WoT, cpart, QKD, QKD / 2, HDIM, 112,
                                                 (size_t)TSEQ * HDIM);
  reduce2_kernel<<<1792, 256, 0, stream>>>(cpart, cpart + (size_t)TSEQ * HDIM, out,
                                           TSEQ * HDIM / 4);
}

// Round 6
// 336.184 us; speedup vs baseline: 1.2177x; 1.0128x over previous
//
#include <hip/hip_runtime.h>
#include <math.h>

typedef __attribute__((ext_vector_type(8))) __bf16 bf16x8;
typedef __attribute__((ext_vector_type(4))) __bf16 bf16x4;
typedef __attribute__((ext_vector_type(4))) float f32x4;

#define TSEQ 2048
#define HDIM 3584
#define NQH  16
#define NKVH 8
#define DH   256
#define WIN  1024
#define QKD  (NQH * DH)   /* 4096 */
#define KVD  (NKVH * DH)  /* 2048 */
#define QKVN 8192         /* fused QKV output width */

#define MFMA __builtin_amdgcn_mfma_f32_16x16x32_bf16

__device__ __forceinline__ void gload_lds16(const void* g, void* l) {
  __builtin_amdgcn_global_load_lds(
      (const __attribute__((address_space(1))) void*)g,
      (__attribute__((address_space(3))) void*)l, 16, 0, 0);
}

// ---------------- prep kernels ----------------

__global__ void cvt_bf16_kernel(const float* __restrict__ in,
                                __bf16* __restrict__ out, long n) {
  long i = ((long)blockIdx.x * blockDim.x + threadIdx.x) * 4;
  if (i >= n) return;
  float4 v = *reinterpret_cast<const float4*>(in + i);
  bf16x4 o4;
  o4.x = (__bf16)v.x; o4.y = (__bf16)v.y; o4.z = (__bf16)v.z; o4.w = (__bf16)v.w;
  *reinterpret_cast<bf16x4*>(out + i) = o4;
}

// in: R x C fp32 -> out: C x R bf16; 64x64 tiles, vectorized both sides
__global__ void transpose_cvt64_kernel(const float* __restrict__ in,
                                       __bf16* __restrict__ out, int R, int C) {
  __shared__ float tile[64][65];
  const int tid = threadIdx.x;  // 256
  const int r0 = blockIdx.y * 64, c0 = blockIdx.x * 64;
#pragma unroll
  for (int it = 0; it < 4; ++it) {
    int f = tid + it * 256;
    int row = f >> 4, c4 = (f & 15) * 4;
    float4 v = *reinterpret_cast<const float4*>(&in[(size_t)(r0 + row) * C + c0 + c4]);
    tile[row][c4] = v.x; tile[row][c4 + 1] = v.y;
    tile[row][c4 + 2] = v.z; tile[row][c4 + 3] = v.w;
  }
  __syncthreads();
#pragma unroll
  for (int it = 0; it < 2; ++it) {
    int s = tid + it * 256;
    int oc = s >> 3, rb = (s & 7) * 8;
    bf16x8 o8;
#pragma unroll
    for (int j = 0; j < 8; ++j) o8[j] = (__bf16)tile[rb + j][oc];
    *reinterpret_cast<bf16x8*>(&out[(size_t)(c0 + oc) * R + r0 + rb]) = o8;
  }
}

// in: R x C bf16 (leading dim ldin) -> out: C x R bf16 (leading dim ldout)
__global__ void transpose_bf16_kernel(const __bf16* __restrict__ in,
                                      __bf16* __restrict__ out, int ldin, int ldout) {
  __shared__ __bf16 tile[32][33];
  const int tx = threadIdx.x, ty = threadIdx.y;
  const int c0 = blockIdx.x * 32, r0 = blockIdx.y * 32;
#pragma unroll
  for (int i = 0; i < 4; ++i)
    tile[ty + i * 8][tx] = in[(size_t)(r0 + ty + i * 8) * ldin + (c0 + tx)];
  __syncthreads();
#pragma unroll
  for (int i = 0; i < 4; ++i)
    out[(size_t)(c0 + ty + i * 8) * ldout + (r0 + tx)] = tile[tx][ty + i * 8];
}

__global__ void rope_table_kernel(const int* __restrict__ positions,
                                  float* __restrict__ ct,
                                  float* __restrict__ st) {
  int i = blockIdx.x * blockDim.x + threadIdx.x;
  if (i >= TSEQ * 128) return;
  int t = i >> 7, j = i & 127;
  float invf = (float)exp((double)(-2 * j) * (9.210340371976184 / 256.0));
  float ang = (float)positions[t] * invf;
  ct[i] = cosf(ang);
  st[i] = sinf(ang);
}

// in-place RoPE on bf16 rows of leading-dim ld; also applies `scale`
__global__ void rope_apply_kernel(__bf16* __restrict__ x,
                                  const float* __restrict__ ct,
                                  const float* __restrict__ st,
                                  int heads, int ld, float scale, int total) {
  int i = blockIdx.x * blockDim.x + threadIdx.x;
  if (i >= total) return;
  int j = i & 127;
  int th = i >> 7;
  int t = th / heads;
  int head = th - t * heads;
  size_t base = (size_t)t * ld + head * DH + j;
  float x1 = (float)x[base], x2 = (float)x[base + 128];
  float c = ct[(t << 7) + j], s = st[(t << 7) + j];
  x[base]       = (__bf16)((x1 * c - x2 * s) * scale);
  x[base + 128] = (__bf16)((x2 * c + x1 * s) * scale);
}

// split-K reduce: out[i] = p0[i] + p1[i]  (fp32, float4-vectorized)
__global__ void reduce2_kernel(const float* __restrict__ p0,
                               const float* __restrict__ p1,
                               float* __restrict__ out, int n4) {
  int stride = gridDim.x * blockDim.x;
  for (int i = blockIdx.x * blockDim.x + threadIdx.x; i < n4; i += stride) {
    float4 a = reinterpret_cast<const float4*>(p0)[i];
    float4 b = reinterpret_cast<const float4*>(p1)[i];
    a.x += b.x; a.y += b.y; a.z += b.z; a.w += b.w;
    reinterpret_cast<float4*>(out)[i] = a;
  }
}

// ---------------- 256x256 8-phase GEMM, 2 K-tiles/iter ----------------
// (unchanged from round 5 — 48% MfmaUtil)

__device__ __forceinline__ void stage_half(const __bf16* __restrict__ gbase,
                                           int row0, int ldg, int k0,
                                           __bf16* lds_half, int tid) {
  const int lane = tid & 63;
  const int w = tid >> 6;
  const int lr = lane >> 3;                    // row&7 within half
  const int swzcol = ((lane & 7) ^ lr) << 3;   // pre-swizzled source column
  const __bf16* g = gbase + (size_t)(row0 + w * 8 + lr) * ldg + k0 + swzcol;
  __bf16* l = lds_half + w * 512;              // wave-uniform dest (elements)
  gload_lds16(g, l);
  gload_lds16(g + (size_t)64 * ldg, l + 4096);
}

#define BAR __builtin_amdgcn_s_barrier()

#define RD_A(DST, BASE, MO)                                         \
  _Pragma("unroll")                                                 \
  for (int m_ = 0; m_ < 4; ++m_) {                                  \
    const __bf16* p_ = (BASE) + (((MO) + m_) * 16 + l15) * 64;      \
    DST[m_][0] = *(const bf16x8*)(p_ + kxa);                        \
    DST[m_][1] = *(const bf16x8*)(p_ + kxb);                        \
  }

#define RD_B(DST, BASE, NO)                                         \
  _Pragma("unroll")                                                 \
  for (int n_ = 0; n_ < 2; ++n_) {                                  \
    const __bf16* p_ = (BASE) + (bro + ((NO) + n_) * 16 + l15) * 64;\
    DST[n_][0] = *(const bf16x8*)(p_ + kxa);                        \
    DST[n_][1] = *(const bf16x8*)(p_ + kxb);                        \
  }

#define MQUAD(AF, BF, MO, NO)                                          \
  __builtin_amdgcn_s_setprio(1);                                       \
  _Pragma("unroll")                                                    \
  for (int m_ = 0; m_ < 4; ++m_)                                       \
    _Pragma("unroll")                                                  \
    for (int n_ = 0; n_ < 2; ++n_) {                                   \
      acc[(MO) + m_][(NO) + n_] =                                      \
          MFMA(AF[m_][0], BF[n_][0], acc[(MO) + m_][(NO) + n_], 0, 0, 0); \
      acc[(MO) + m_][(NO) + n_] =                                      \
          MFMA(AF[m_][1], BF[n_][1], acc[(MO) + m_][(NO) + n_], 0, 0, 0); \
    }                                                                  \
  __builtin_amdgcn_s_setprio(0);

template <typename CT>
__global__ __launch_bounds__(512, 2) void gemm256_kernel(
    const __bf16* __restrict__ A, const __bf16* __restrict__ B,
    CT* __restrict__ C, int lda, int Klen, int ldc, int nrc, size_t cstride) {
  __shared__ __bf16 lds[2][2][2][8192];  // [tile-parity][A=0/B=1][half][128*64]

  const int nwg = gridDim.x;
  const int per = nwg >> 3;
  const int wg = (blockIdx.x & 7) * per + (blockIdx.x >> 3);  // XCD chunk swizzle
  const int kslice = wg / nrc;
  const int rem = wg - kslice * nrc;
  const int row0 = (rem & 7) * 256;        // col-major decode: XCD owns col-band
  const int col0 = (rem >> 3) * 256;
  const int k0 = kslice * Klen;
  CT* Cs = C + (size_t)kslice * cstride;

  const int tid = threadIdx.x;
  const int lane = tid & 63, w = tid >> 6;
  const int wr = w >> 2, wc = w & 3;
  const int l15 = lane & 15, lg = lane >> 4;
  const int swz = (lane & 7) << 3;
  const int kxa = (lg * 8) ^ swz;        // ksub 0
  const int kxb = (32 + lg * 8) ^ swz;   // ksub 1
  const int bro = (wc & 1) * 64;

  const __bf16* Ablk = A + (size_t)row0 * lda + k0;
  const __bf16* Bblk = B + (size_t)col0 * lda + k0;

  const __bf16* Ae = &lds[0][0][wr][0];
  const __bf16* Be = &lds[0][1][wc >> 1][0];
  const __bf16* Ao = &lds[1][0][wr][0];
  const __bf16* Bo = &lds[1][1][wc >> 1][0];

  f32x4 acc[8][4] = {};
  const int NT = Klen >> 6;
  const int NI = NT >> 1;

  // prologue: tile0 all halves -> buf0; tile1 A halves -> buf1
  stage_half(Ablk, 0,   lda, 0,  &lds[0][0][0][0], tid);
  stage_half(Ablk, 128, lda, 0,  &lds[0][0][1][0], tid);
  stage_half(Bblk, 0,   lda, 0,  &lds[0][1][0][0], tid);
  stage_half(Bblk, 128, lda, 0,  &lds[0][1][1][0], tid);
  stage_half(Ablk, 0,   lda, 64, &lds[1][0][0][0], tid);
  stage_half(Ablk, 128, lda, 64, &lds[1][0][1][0], tid);
  asm volatile("s_waitcnt vmcnt(4)" ::: "memory");
  BAR;

  bf16x8 a03[4][2], a47[4][2], b01[2][2], b23[2][2];

  for (int j = 0; j < NI; ++j) {
    const int e = 2 * j, o = 2 * j + 1;
    const bool last = (j == NI - 1);

    // ---- ph1: read e.A03 + e.B01; stage B0(o)->buf1
    RD_A(a03, Ae, 0);
    RD_B(b01, Be, 0);
    stage_half(Bblk, 0, lda, o * 64, &lds[1][1][0][0], tid);
    asm volatile("s_waitcnt lgkmcnt(8)" ::: "memory");
    BAR; MQUAD(a03, b01, 0, 0); BAR;

    // ---- ph2: read e.A47; stage B1(o)->buf1
    RD_A(a47, Ae, 4);
    stage_half(Bblk, 128, lda, o * 64, &lds[1][1][1][0], tid);
    BAR; MQUAD(a47, b01, 4, 0); BAR;

    // ---- ph3: read e.B23; stage A0(e+2)->buf0 (buf0.A free after ph2 bar)
    RD_B(b23, Be, 2);
    if (!last) stage_half(Ablk, 0, lda, (e + 2) * 64, &lds[0][0][0][0], tid);
    BAR; MQUAD(a47, b23, 4, 2); BAR;

    // ---- ph4: stage A1(e+2)->buf0; counted vmcnt -> tile o fully landed
    if (!last) {
      stage_half(Ablk, 128, lda, (e + 2) * 64, &lds[0][0][1][0], tid);
      asm volatile("s_waitcnt vmcnt(4)" ::: "memory");
    } else {
      asm volatile("s_waitcnt vmcnt(0)" ::: "memory");
    }
    BAR; MQUAD(a03, b23, 0, 2); BAR;

    // ---- ph5: read o.A03 + o.B01; stage B0(e+2)->buf0 (buf0.B free after ph3)
    RD_A(a03, Ao, 0);
    RD_B(b01, Bo, 0);
    if (!last) stage_half(Bblk, 0, lda, (e + 2) * 64, &lds[0][1][0][0], tid);
    asm volatile("s_waitcnt lgkmcnt(8)" ::: "memory");
    BAR; MQUAD(a03, b01, 0, 0); BAR;

    // ---- ph6: read o.A47; stage B1(e+2)->buf0
    RD_A(a47, Ao, 4);
    if (!last) stage_half(Bblk, 128, lda, (e + 2) * 64, &lds[0][1][1][0], tid);
    BAR; MQUAD(a47, b01, 4, 0); BAR;

    // ---- ph7: read o.B23; stage A0(o+2)->buf1 (buf1.A free after ph6 bar)
    RD_B(b23, Bo, 2);
    if (!last) stage_half(Ablk, 0, lda, (o + 2) * 64, &lds[1][0][0][0], tid);
    BAR; MQUAD(a47, b23, 4, 2); BAR;

    // ---- ph8: stage A1(o+2)->buf1; counted vmcnt -> tile e+2 fully landed
    if (!last) {
      stage_half(Ablk, 128, lda, (o + 2) * 64, &lds[1][0][1][0], tid);
      asm volatile("s_waitcnt vmcnt(4)" ::: "memory");
    }
    BAR; MQUAD(a03, b23, 0, 2); BAR;
  }

#pragma unroll
  for (int m = 0; m < 8; ++m)
#pragma unroll
    for (int n = 0; n < 4; ++n)
#pragma unroll
      for (int r = 0; r < 4; ++r) {
        int row = row0 + wr * 128 + m * 16 + lg * 4 + r;
        int col = col0 + wc * 64 + n * 16 + l15;
        Cs[(size_t)row * ldc + col] = (CT)acc[m][n][r];
      }
}

// ---------------- flash attention (GQA-merged, reg-prefetch) ----------------
// grid = (32 q-tiles of 64, 8 kv-heads), 512 threads = 8 waves.
// Waves 0-3 -> q-head 2h (16 rows each); waves 4-7 -> q-head 2h+1.
// K/V staged ONCE per block; next tile prefetched into regs during compute.
// Fixed-max softmax (|s|<=50): p = exp(-100/(e^{.04x}+1)), no rescale.
__global__ __launch_bounds__(512, 2) void attn_kernel(
    const __bf16* __restrict__ q, const __bf16* __restrict__ k,
    const __bf16* __restrict__ vt, __bf16* __restrict__ o) {
  __shared__ __bf16 Klds[64][264];   // keys x d, +8 pad
  __shared__ __bf16 Vlds[256][72];   // d x keys, +8 pad
  __shared__ __bf16 Plds[8][16][72]; // per-wave P round-trip

  const int tid = threadIdx.x;
  const int wave = tid >> 6;
  const int lane = tid & 63;
  const int l16 = lane & 15;
  const int lg = lane >> 4;
  const int h = blockIdx.y;              // kv head
  const int qh = 2 * h + (wave >> 2);    // q head
  const int wsub = wave & 3;
  const int q0 = blockIdx.x << 6;
  const int qr = q0 + wsub * 16;

  bf16x8 qf[8];
  {
    const __bf16* qp = q + (size_t)(qr + l16) * QKVN + qh * DH + lg * 8;
#pragma unroll
    for (int ds = 0; ds < 8; ++ds)
      qf[ds] = *reinterpret_cast<const bf16x8*>(qp + ds * 32);
  }

  f32x4 accO[16] = {};
  float l_run[4] = {0.f, 0.f, 0.f, 0.f};

  int t_lo = q0 - (WIN - 1);
  if (t_lo < 0) t_lo = 0;
  t_lo &= ~63;

  const __bf16* kg0 = k + (size_t)h * DH;
  const __bf16* vg0 = vt + (size_t)(h * DH) * TSEQ;

  // prime: tile t_lo -> regs
  bf16x8 kpre[4], vpre[4];
#pragma unroll
  for (int it = 0; it < 4; ++it) {
    int c = tid + it * 512;
    kpre[it] = *reinterpret_cast<const bf16x8*>(
        kg0 + (size_t)(t_lo + (c >> 5)) * QKVN + (c & 31) * 8);
    vpre[it] = *reinterpret_cast<const bf16x8*>(
        vg0 + (size_t)(c >> 3) * TSEQ + t_lo + (c & 7) * 8);
  }

  for (int t0 = t_lo; t0 <= q0; t0 += 64) {
    __syncthreads();
#pragma unroll
    for (int it = 0; it < 4; ++it) {
      int c = tid + it * 512;
      *reinterpret_cast<bf16x8*>(&Klds[c >> 5][(c & 31) * 8]) = kpre[it];
      *reinterpret_cast<bf16x8*>(&Vlds[c >> 3][(c & 7) * 8]) = vpre[it];
    }
    __syncthreads();

    if (t0 + 64 <= q0) {
      const int tn = t0 + 64;
#pragma unroll
      for (int it = 0; it < 4; ++it) {
        int c = tid + it * 512;
        kpre[it] = *reinterpret_cast<const bf16x8*>(
            kg0 + (size_t)(tn + (c >> 5)) * QKVN + (c & 31) * 8);
        vpre[it] = *reinterpret_cast<const bf16x8*>(
            vg0 + (size_t)(c >> 3) * TSEQ + tn + (c & 7) * 8);
      }
    }

    f32x4 accS[4] = {};
    __builtin_amdgcn_s_setprio(1);
#pragma unroll
    for (int nt = 0; nt < 4; ++nt)
#pragma unroll
      for (int ds = 0; ds < 8; ++ds) {
        bf16x8 kf = *reinterpret_cast<const bf16x8*>(&Klds[nt * 16 + l16][ds * 32 + lg * 8]);
        accS[nt] = MFMA(qf[ds], kf, accS[nt], 0, 0, 0);
      }
    __builtin_amdgcn_s_setprio(0);

    // fused softcap+exp with fixed max=50; p in [0,1]
    float rs[4] = {0.f, 0.f, 0.f, 0.f};
#pragma unroll
    for (int nt = 0; nt < 4; ++nt) {
      int key = t0 + nt * 16 + l16;
#pragma unroll
      for (int r = 0; r < 4; ++r) {
        int row = qr + lg * 4 + r;
        float t = __expf(accS[nt][r] * 0.04f);
        float p = __expf(-100.0f / (t + 1.0f));
        bool valid = (key <= row) && (row - key < WIN);
        p = valid ? p : 0.f;
        rs[r] += p;
        Plds[wave][lg * 4 + r][nt * 16 + l16] = (__bf16)p;
      }
    }
#pragma unroll
    for (int off = 1; off < 16; off <<= 1)
#pragma unroll
      for (int r = 0; r < 4; ++r)
        rs[r] += __shfl_xor(rs[r], off);
#pragma unroll
    for (int r = 0; r < 4; ++r)
      l_run[r] += rs[r];

    __builtin_amdgcn_s_setprio(1);
#pragma unroll
    for (int ks = 0; ks < 2; ++ks) {
      bf16x8 pa = *reinterpret_cast<const bf16x8*>(&Plds[wave][l16][ks * 32 + lg * 8]);
#pragma unroll
      for (int nt2 = 0; nt2 < 16; ++nt2) {
        bf16x8 vb = *reinterpret_cast<const bf16x8*>(&Vlds[nt2 * 16 + l16][ks * 32 + lg * 8]);
        accO[nt2] = MFMA(pa, vb, accO[nt2], 0, 0, 0);
      }
    }
    __builtin_amdgcn_s_setprio(0);
  }

#pragma unroll
  for (int r = 0; r < 4; ++r) {
    float inv_l = 1.f / l_run[r];
    int row = qr + lg * 4 + r;
#pragma unroll
    for (int nt2 = 0; nt2 < 16; ++nt2)
      o[(size_t)row * QKD + qh * DH + nt2 * 16 + l16] = (__bf16)(accO[nt2][r] * inv_l);
  }
}

// ---------------- launcher ----------------

extern "C" void kernel_launch(void* const* d_in, const int* in_sizes, int n_in,
                              void* d_out, int out_size, void* d_ws, size_t ws_size,
                              hipStream_t stream) {
  const float* hs = (const float*)d_in[0];
  const float* Wq = (const float*)d_in[1];
  const float* Wk = (const float*)d_in[2];
  const float* Wv = (const float*)d_in[3];
  const float* Wo = (const float*)d_in[4];
  const int* positions = (const int*)d_in[5];
  float* out = (float*)d_out;

  char* ws = (char*)d_ws;
  const size_t SZ_HS  = (size_t)TSEQ * HDIM * 2;
  const size_t SZ_WQT = (size_t)QKD * HDIM * 2;
  const size_t SZ_WKT = (size_t)KVD * HDIM * 2;
  const size_t SZ_WOT = (size_t)HDIM * QKD * 2;
  const size_t SZ_QKV = (size_t)TSEQ * QKVN * 2;
  const size_t SZ_O   = (size_t)TSEQ * QKD * 2;
  const size_t SZ_TBL = (size_t)TSEQ * 128 * 4;

  __bf16* hs_bf = (__bf16*)ws; ws += SZ_HS;
  __bf16* WqT   = (__bf16*)ws; ws += SZ_WQT;   // WqT/WkT/WvT contiguous -> fused B (8192 x 3584)
  __bf16* WkT   = (__bf16*)ws; ws += SZ_WKT;
  __bf16* WvT   = (__bf16*)ws; ws += SZ_WKT;
  __bf16* WoT   = (__bf16*)ws; ws += SZ_WOT;
  __bf16* qkv   = (__bf16*)ws; ws += SZ_QKV;
  __bf16* o_bf  = (__bf16*)ws; ws += SZ_O;
  float*  cost  = (float*)ws;  ws += SZ_TBL;
  float*  sint  = (float*)ws;  ws += SZ_TBL;
  __bf16* vt_bf = hs_bf;          // overlay: hs_bf dead after QKV GEMM
  float* cpart = (float*)WqT;     // overlay: W{q,k,v}T (58.72MB) dead after QKV GEMM
  if ((size_t)(ws - (char*)d_ws) > ws_size) return;

  // prep
  cvt_bf16_kernel<<<(TSEQ * HDIM) / 1024, 256, 0, stream>>>(hs, hs_bf, (long)TSEQ * HDIM);
  transpose_cvt64_kernel<<<dim3(QKD / 64, HDIM / 64), 256, 0, stream>>>(Wq, WqT, HDIM, QKD);
  transpose_cvt64_kernel<<<dim3(KVD / 64, HDIM / 64), 256, 0, stream>>>(Wk, WkT, HDIM, KVD);
  transpose_cvt64_kernel<<<dim3(KVD / 64, HDIM / 64), 256, 0, stream>>>(Wv, WvT, HDIM, KVD);
  transpose_cvt64_kernel<<<dim3(HDIM / 64, QKD / 64), 256, 0, stream>>>(Wo, WoT, QKD, HDIM);
  rope_table_kernel<<<(TSEQ * 128) / 256, 256, 0, stream>>>(positions, cost, sint);

  // fused QKV projection: M=2048, N=8192, K=3584 -> 256 blocks (1/CU)
  gemm256_kernel<__bf16><<<256, 512, 0, stream>>>(hs_bf, WqT, qkv, HDIM, HDIM, QKVN, 256, 0);

  // RoPE (+ q scale 1/16), V transpose (into hs_bf overlay)
  rope_apply_kernel<<<(TSEQ * NQH * 128) / 256, 256, 0, stream>>>(qkv, cost, sint, NQH, QKVN, 0.0625f, TSEQ * NQH * 128);
  rope_apply_kernel<<<(TSEQ * NKVH * 128) / 256, 256, 0, stream>>>(qkv + QKD, cost, sint, NKVH, QKVN, 1.0f, TSEQ * NKVH * 128);
  transpose_bf16_kernel<<<dim3(KVD / 32, TSEQ / 32), dim3(32, 8), 0, stream>>>(qkv + QKD + KVD, vt_bf, QKVN, TSEQ);

  // attention: 256 blocks (1/CU), head-pair merged
  attn_kernel<<<dim3(TSEQ / 64, NKVH), 512, 0, stream>>>(qkv, qkv + QKD, vt_bf, o_bf);

  // output projection: M=2048, N=3584, K=4096, split-K=2 -> 224 blocks
  gemm256_kernel<float><<<224, 512, 0, stream>>>(o_bf, WoT, cpart, QKD, QKD / 2, HDIM, 112,
                                                 (size_t)TSEQ * HDIM);
  reduce2_kernel<<<1792, 256, 0, stream>>>(cpart, cpart + (size_t)TSEQ * HDIM, out,
                                           TSEQ * HDIM / 4);
}